// Round 6
// baseline (620.387 us; speedup 1.0000x reference)
//
#include <hip/hip_runtime.h>
#include <hip/hip_bf16.h>

typedef unsigned short u16;
typedef __attribute__((ext_vector_type(8))) short bf16x8;
typedef __attribute__((ext_vector_type(4))) float f32x4;

#define N_TOK 4096
#define DMODEL 3072
#define NH 16
#define DHEAD 64
#define INNER 1024
#define SCALE_LOG2E 0.18033688011112042f  /* (1/8) * log2(e) */

__device__ __forceinline__ u16 f2bf(float f) {
    union { float f; unsigned u; } un; un.f = f;
    unsigned r = un.u + 0x7fffu + ((un.u >> 16) & 1u);
    return (u16)(r >> 16);
}
__device__ __forceinline__ float bf2f(u16 u) {
    union { unsigned u; float f; } x; x.u = ((unsigned)u) << 16; return x.f;
}
// pack two f32 -> two bf16 (round-half-up) in 3 VALU ops; a -> low 16
__device__ __forceinline__ unsigned pk2bf(float a, float b) {
    union { float f; unsigned u; } ua, ub; ua.f = a; ub.f = b;
    return __builtin_amdgcn_perm(ub.u + 0x8000u, ua.u + 0x8000u, 0x07060302u);
}
__device__ __forceinline__ void load_lds16(const u16* g, u16* l) {
    __builtin_amdgcn_global_load_lds(
        (const __attribute__((address_space(1))) unsigned int*)g,
        (__attribute__((address_space(3))) unsigned int*)l, 16, 0, 0);
}

// Build PV B-operand in-register from packed exp2(S^T) words.
// Inputs: u0,u1 = key pairs (4q+0,1)/(4q+2,3) of lower 16 keys (s[lo]);
//         w0,w1 = same for upper 16 keys (s[hi]).
// Output: lane (l15,quad) holds keys [8*quad, 8*quad+8) for col q=l15.
// swap32: new0={old0.lo,old1.lo}; swap16: new0=[o0@g0,o1@g0,o0@g2,o1@g2].
__device__ __forceinline__ bf16x8 build_bp(unsigned u0, unsigned u1,
                                           unsigned w0, unsigned w1) {
    auto a = __builtin_amdgcn_permlane32_swap(u0, w0, false, false);
    auto b = __builtin_amdgcn_permlane16_swap(a[0], a[1], false, false);
    auto c = __builtin_amdgcn_permlane32_swap(u1, w1, false, false);
    auto d = __builtin_amdgcn_permlane16_swap(c[0], c[1], false, false);
    union { unsigned w[4]; bf16x8 v; } r;
    r.w[0] = b[0]; r.w[1] = d[0]; r.w[2] = b[1]; r.w[3] = d[1];
    return r.v;
}

// ------- Fused prep: LN rows (blocks 0..4095), wq cvt (4096..6143), --------
// ------- wo cvt (6144..6655). --------
__global__ __launch_bounds__(256) void prep(const float* __restrict__ x,
                                            const float* __restrict__ g,
                                            const float* __restrict__ b,
                                            u16* __restrict__ xn,
                                            const float* __restrict__ w_qkv,
                                            u16* __restrict__ wq,
                                            const float* __restrict__ w_out,
                                            u16* __restrict__ wo) {
    int bid = blockIdx.x;
    int tid = threadIdx.x;
    if (bid < 4096) {
        int row = bid;
        const float4* xr = (const float4*)(x + (size_t)row * DMODEL);
        float4 v[3];
        float s = 0.f, ss = 0.f;
#pragma unroll
        for (int i = 0; i < 3; ++i) {
            v[i] = xr[i * 256 + tid];
            s  += v[i].x + v[i].y + v[i].z + v[i].w;
            ss += v[i].x * v[i].x + v[i].y * v[i].y + v[i].z * v[i].z + v[i].w * v[i].w;
        }
#pragma unroll
        for (int off = 32; off; off >>= 1) {
            s  += __shfl_xor(s, off);
            ss += __shfl_xor(ss, off);
        }
        __shared__ float red[8];
        int wid = tid >> 6, lane = tid & 63;
        if (lane == 0) { red[wid] = s; red[wid + 4] = ss; }
        __syncthreads();
        s  = red[0] + red[1] + red[2] + red[3];
        ss = red[4] + red[5] + red[6] + red[7];
        float mean = s * (1.f / DMODEL);
        float var  = ss * (1.f / DMODEL) - mean * mean;
        float rstd = rsqrtf(var + 1e-5f);
        ushort4* orow = (ushort4*)(xn + (size_t)row * DMODEL);
#pragma unroll
        for (int i = 0; i < 3; ++i) {
            float4 gg = ((const float4*)g)[i * 256 + tid];
            float4 bb = ((const float4*)b)[i * 256 + tid];
            ushort4 o;
            o.x = f2bf((v[i].x - mean) * rstd * gg.x + bb.x);
            o.y = f2bf((v[i].y - mean) * rstd * gg.y + bb.y);
            o.z = f2bf((v[i].z - mean) * rstd * gg.z + bb.z);
            o.w = f2bf((v[i].w - mean) * rstd * gg.w + bb.w);
            orow[i * 256 + tid] = o;
        }
    } else if (bid < 4096 + 2048) {
        const int n4 = 3 * INNER * DMODEL / 4;
        for (int i = (bid - 4096) * 256 + tid; i < n4; i += 2048 * 256) {
            float4 v = ((const float4*)w_qkv)[i];
            ushort4 o;
            o.x = f2bf(v.x); o.y = f2bf(v.y); o.z = f2bf(v.z); o.w = f2bf(v.w);
            ((ushort4*)wq)[i] = o;
        }
    } else {
        const int n4 = DMODEL * INNER / 4;
        for (int i = (bid - 6144) * 256 + tid; i < n4; i += 512 * 256) {
            float4 v = ((const float4*)w_out)[i];
            ushort4 o;
            o.x = f2bf(v.x); o.y = f2bf(v.y); o.z = f2bf(v.z); o.w = f2bf(v.w);
            ((ushort4*)wo)[i] = o;
        }
    }
}

// ============ GEMM 256x256 8-phase (T2+T3+T4+T5), C = A * B^T ============
// (unchanged — verified R2-R5; control)

#define VM6 asm volatile("s_waitcnt vmcnt(6)" ::: "memory")
#define VM4 asm volatile("s_waitcnt vmcnt(4)" ::: "memory")
#define VM2 asm volatile("s_waitcnt vmcnt(2)" ::: "memory")
#define VM0 asm volatile("s_waitcnt vmcnt(0)" ::: "memory")
#define LGK8 asm volatile("s_waitcnt lgkmcnt(8)" ::: "memory")
#define NOPS ((void)0)

#define ST_A(d, h, t) do { \
    load_lds16(pA##h##0 + (size_t)(t) * 64, &lds[(d) * 16384 + (h) * 8192 + dq]); \
    load_lds16(pA##h##1 + (size_t)(t) * 64, &lds[(d) * 16384 + (h) * 8192 + dq + 512]); \
  } while (0)
#define ST_B(d, h, t) do { \
    load_lds16(pB##h##0 + (size_t)(t) * 64, &lds[32768 + (d) * 16384 + (h) * 8192 + dq]); \
    load_lds16(pB##h##1 + (size_t)(t) * 64, &lds[32768 + (d) * 16384 + (h) * 8192 + dq + 512]); \
  } while (0)

#define PHASE(d, p, STAGE, PRE, POST) do { \
    bf16x8 afr[2][2]; \
    if ((p) == 0) { \
      _Pragma("unroll") for (int nf = 0; nf < 4; ++nf) { \
        bfr[nf][0] = *(const bf16x8*)&lds[(d) * 16384 + baseB + nf * 1024 + c0]; \
        bfr[nf][1] = *(const bf16x8*)&lds[(d) * 16384 + baseB + nf * 1024 + c1]; \
      } \
    } \
    _Pragma("unroll") for (int mfl = 0; mfl < 2; ++mfl) { \
      afr[mfl][0] = *(const bf16x8*)&lds[(d) * 16384 + (p) * 4096 + mfl * 1024 + baseA + c0]; \
      afr[mfl][1] = *(const bf16x8*)&lds[(d) * 16384 + (p) * 4096 + mfl * 1024 + baseA + c1]; \
    } \
    STAGE; \
    PRE; \
    __builtin_amdgcn_s_barrier(); \
    asm volatile("s_waitcnt lgkmcnt(0)" ::: "memory"); \
    __builtin_amdgcn_sched_barrier(0); \
    __builtin_amdgcn_s_setprio(1); \
    _Pragma("unroll") for (int mfl = 0; mfl < 2; ++mfl) \
      _Pragma("unroll") for (int nf = 0; nf < 4; ++nf) { \
        acc[(p) * 2 + mfl][nf] = __builtin_amdgcn_mfma_f32_16x16x32_bf16(afr[mfl][0], bfr[nf][0], acc[(p) * 2 + mfl][nf], 0, 0, 0); \
        acc[(p) * 2 + mfl][nf] = __builtin_amdgcn_mfma_f32_16x16x32_bf16(afr[mfl][1], bfr[nf][1], acc[(p) * 2 + mfl][nf], 0, 0, 0); \
      } \
    __builtin_amdgcn_s_setprio(0); \
    POST; \
    __builtin_amdgcn_s_barrier(); \
  } while (0)

template <int CBF16>
__global__ __launch_bounds__(512, 2) void gemm256(const u16* __restrict__ A,
                                                  const u16* __restrict__ B,
                                                  void* __restrict__ C,
                                                  int M, int Nn, int K) {
    __shared__ u16 lds[65536];   // A: [2][256][64] @0 ; B: same @32768 (128 KiB)
    const int tid = threadIdx.x;
    const int lane = tid & 63, wid = tid >> 6;
    const int wm = wid >> 2, wn = wid & 3;
    const int l15 = lane & 15, quad = lane >> 4;
    const int sw = l15 & 7;

    // XCD-aware bijective swizzle (gridDim.x % 8 == 0)
    int nbx = Nn >> 8;
    int cpx = gridDim.x >> 3;
    int wg = (blockIdx.x & 7) * cpx + (blockIdx.x >> 3);
    int m0 = (wg / nbx) << 8, n0 = (wg % nbx) << 8;

    // per-thread ds_read bases (u16 units) and swizzled chunk offsets
    const int baseA = wm * 2048 + l15 * 64;
    const int baseB = 32768 + wn * 4096 + l15 * 64;
    const int c0 = (quad ^ sw) * 8;
    const int c1 = ((4 + quad) ^ sw) * 8;
    const int dq = wid * 1024;                 // stage LDS base (j adds 512)

    // stage source pointers: LDS row ell -> global row, pre-swizzled col
    const u16 *pA00, *pA01, *pA10, *pA11, *pB00, *pB01, *pB10, *pB11;
    {
        int scol = ((lane & 7) ^ (lane >> 3)) * 8;
#define MKSRC(h, j, PA, PB) { \
        int ell = (h) * 128 + (wid * 2 + (j)) * 8 + (lane >> 3); \
        int g = ell >> 6, wmh = (ell >> 5) & 1, r = ell & 31; \
        PA = A + (size_t)(m0 + wmh * 128 + g * 32 + r) * K + scol; \
        PB = B + (size_t)(n0 + ell) * K + scol; }
        MKSRC(0, 0, pA00, pB00) MKSRC(0, 1, pA01, pB01)
        MKSRC(1, 0, pA10, pB10) MKSRC(1, 1, pA11, pB11)
#undef MKSRC
    }

    f32x4 acc[8][4];
    f32x4 zero4 = {0.f, 0.f, 0.f, 0.f};
#pragma unroll
    for (int i = 0; i < 8; ++i)
#pragma unroll
        for (int j = 0; j < 4; ++j) acc[i][j] = zero4;
    bf16x8 bfr[4][2];

    // prologue: tile0 (4 halves) -> buf0, tile1 (B0,B1,A0) -> buf1
    ST_B(0, 0, 0); ST_B(0, 1, 0); ST_A(0, 0, 0); ST_A(0, 1, 0);
    ST_B(1, 0, 1); ST_B(1, 1, 1); ST_A(1, 0, 1);
    VM6;                                   // tile0 landed; 3 halves in flight
    __builtin_amdgcn_s_barrier();

    const int NIT = (K >> 7) - 1;          // T/2 - 1 iterations
    for (int i = 0; i < NIT; ++i) {
        int t = 2 * i;
        PHASE(0, 0, ST_A(1, 1, t + 1), LGK8, NOPS);
        PHASE(0, 1, ST_B(0, 0, t + 2), NOPS, NOPS);
        PHASE(0, 2, ST_B(0, 1, t + 2), NOPS, NOPS);
        PHASE(0, 3, ST_A(0, 0, t + 2), NOPS, VM6);
        PHASE(1, 0, ST_A(0, 1, t + 2), LGK8, NOPS);
        PHASE(1, 1, ST_B(1, 0, t + 3), NOPS, NOPS);
        PHASE(1, 2, ST_B(1, 1, t + 3), NOPS, NOPS);
        PHASE(1, 3, ST_A(1, 0, t + 3), NOPS, VM6);
    }
    {   // epilogue: tiles T-2 (buf0), T-1 (buf1); only (T-1).A1 left to stage
        int T = K >> 6;
        PHASE(0, 0, ST_A(1, 1, T - 1), LGK8, NOPS);
        PHASE(0, 1, NOPS, NOPS, NOPS);
        PHASE(0, 2, NOPS, NOPS, NOPS);
        PHASE(0, 3, NOPS, NOPS, VM0);
        PHASE(1, 0, NOPS, LGK8, NOPS);
        PHASE(1, 1, NOPS, NOPS, NOPS);
        PHASE(1, 2, NOPS, NOPS, NOPS);
        PHASE(1, 3, NOPS, NOPS, NOPS);
    }

    // C write: rr = m0 + wm*128 + mf*16 + quad*4 + r ; cc = n0 + wn*64 + nf*16 + l15
#pragma unroll
    for (int mf = 0; mf < 8; ++mf)
#pragma unroll
        for (int nf = 0; nf < 4; ++nf)
#pragma unroll
            for (int r = 0; r < 4; ++r) {
                int rr = m0 + wm * 128 + mf * 16 + quad * 4 + r;
                int cc = n0 + wn * 64 + nf * 16 + l15;
                if (CBF16)
                    ((u16*)C)[(size_t)rr * Nn + cc] = f2bf(acc[mf][nf][r]);
                else
                    ((float*)C)[(size_t)rr * Nn + cc] = acc[mf][nf][r];
            }
}

// ------- Fused RoPE (blocks 0..4095) + V transpose (4096..5119) -----------
__global__ __launch_bounds__(256) void rope_vt(const u16* __restrict__ qkv,
                                               const float* __restrict__ pe,
                                               u16* __restrict__ Qr,
                                               u16* __restrict__ Kr,
                                               u16* __restrict__ Vt) {
    int bid = blockIdx.x;
    int tid = threadIdx.x;
    if (bid < 4096) {
        int n = bid;
        const u16* qrow = qkv + (size_t)n * DMODEL;
        const float4* pen = (const float4*)(pe + (size_t)n * 128);
#pragma unroll
        for (int it = 0; it < 2; ++it) {
            int p = it * 256 + tid;      // pair index 0..511
            int h = p >> 5, i = p & 31;
            float4 w = pen[i];
            size_t obase = ((size_t)h * N_TOK + n) * DHEAD + 2 * i;
            unsigned qq = *(const unsigned*)&qrow[h * 64 + 2 * i];
            float q0 = bf2f((u16)qq), q1 = bf2f((u16)(qq >> 16));
            *(unsigned*)&Qr[obase] = pk2bf((w.x * q0 + w.y * q1) * SCALE_LOG2E,
                                           (w.z * q0 + w.w * q1) * SCALE_LOG2E);
            unsigned kk = *(const unsigned*)&qrow[INNER + h * 64 + 2 * i];
            float k0 = bf2f((u16)kk), k1 = bf2f((u16)(kk >> 16));
            *(unsigned*)&Kr[obase] = pk2bf(w.x * k0 + w.y * k1, w.z * k0 + w.w * k1);
        }
    } else {
        __shared__ u16 t[64][65];
        int tb = bid - 4096;
        int n0 = (tb & 63) * 64;
        int h = tb >> 6;
#pragma unroll
        for (int it = 0; it < 4; ++it) {
            int nr = it * 16 + (tid >> 4);
            int dc = (tid & 15) * 4;
            ushort4 v = *(const ushort4*)&qkv[(size_t)(n0 + nr) * DMODEL + 2 * INNER + h * 64 + dc];
            t[dc + 0][nr] = v.x; t[dc + 1][nr] = v.y; t[dc + 2][nr] = v.z; t[dc + 3][nr] = v.w;
        }
        __syncthreads();
#pragma unroll
        for (int it = 0; it < 4; ++it) {
            int dr = it * 16 + (tid >> 4);
            int nc = (tid & 15) * 4;
            ushort4 v;
            v.x = t[dr][nc]; v.y = t[dr][nc + 1]; v.z = t[dr][nc + 2]; v.w = t[dr][nc + 3];
            *(ushort4*)&Vt[((size_t)h * 64 + dr) * N_TOK + n0 + nc] = v;
        }
    }
}

// ---------------- Flash attention: 8 waves x 32 q-rows (QBLK 256) ---------
// R6: amortize per-tile block overhead over 2x q-rows and halve staging
// traffic. grid (16 qtiles, 16 heads), 512 thr = 8 waves, each wave owns
// 32 q-rows (mtQ=2 — R4's verified per-wave compute, byte-identical).
// Each wave stages 8 K-rows + 8 V-rows per tile (2 global_load_lds) ->
// counted vmcnt(2), 2-deep dbuf. 2 blocks/CU = 16 waves/CU = 4/SIMD.
// T5 setprio around MFMA clusters (catalog: +4-7% on attn).

#define FA_STAGE(d, kt) do { \
    load_lds16(&Kh[(size_t)((kt) + krow) * DHEAD + csw], &lds_all[(d) * 8192 + kbase]); \
    load_lds16(&Vh[(size_t)krow * N_TOK + (kt) + csw], &lds_all[(d) * 8192 + 4096 + kbase]); \
  } while (0)

#define FA_TILE(d, STAGE_STMT, WAIT_STMT) do { \
    bf16x8 bk[4][2], av[4][2]; \
    _Pragma("unroll") for (int tt = 0; tt < 4; ++tt) \
      _Pragma("unroll") for (int kc = 0; kc < 2; ++kc) { \
        int off = (d) * 8192 + (tt * 16 + l15) * 64 + (((kc * 4 + quad) ^ sw) * 8); \
        bk[tt][kc] = *(const bf16x8*)&lds_all[off]; \
        av[tt][kc] = *(const bf16x8*)&lds_all[off + 4096]; \
      } \
    asm volatile("s_waitcnt lgkmcnt(0)" ::: "memory"); \
    __builtin_amdgcn_sched_barrier(0); \
    __builtin_amdgcn_s_barrier(); \
    __builtin_amdgcn_sched_barrier(0); \
    STAGE_STMT; \
    _Pragma("unroll") for (int mtQ = 0; mtQ < 2; ++mtQ) { \
      f32x4 s[4]; \
      __builtin_amdgcn_s_setprio(1); \
      _Pragma("unroll") for (int ntK = 0; ntK < 4; ++ntK) { \
        f32x4 t0 = __builtin_amdgcn_mfma_f32_16x16x32_bf16(bk[ntK][0], aq[mtQ][0], zero4, 0, 0, 0); \
        s[ntK] = __builtin_amdgcn_mfma_f32_16x16x32_bf16(bk[ntK][1], aq[mtQ][1], t0, 0, 0, 0); \
      } \
      __builtin_amdgcn_s_setprio(0); \
      unsigned pw[4][2]; \
      _Pragma("unroll") for (int ntK = 0; ntK < 4; ++ntK) { \
        pw[ntK][0] = pk2bf(__builtin_amdgcn_exp2f(s[ntK][0]), __builtin_amdgcn_exp2f(s[ntK][1])); \
        pw[ntK][1] = pk2bf(__builtin_amdgcn_exp2f(s[ntK][2]), __builtin_amdgcn_exp2f(s[ntK][3])); \
      } \
      bf16x8 bp0 = build_bp(pw[0][0], pw[0][1], pw[1][0], pw[1][1]); \
      bf16x8 bp1 = build_bp(pw[2][0], pw[2][1], pw[3][0], pw[3][1]); \
      __builtin_amdgcn_s_setprio(1); \
      lacc[mtQ] = __builtin_amdgcn_mfma_f32_16x16x32_bf16(ones, bp0, lacc[mtQ], 0, 0, 0); \
      lacc[mtQ] = __builtin_amdgcn_mfma_f32_16x16x32_bf16(ones, bp1, lacc[mtQ], 0, 0, 0); \
      _Pragma("unroll") for (int dt = 0; dt < 4; ++dt) { \
        o[mtQ][dt] = __builtin_amdgcn_mfma_f32_16x16x32_bf16(av[dt][0], bp0, o[mtQ][dt], 0, 0, 0); \
        o[mtQ][dt] = __builtin_amdgcn_mfma_f32_16x16x32_bf16(av[dt][1], bp1, o[mtQ][dt], 0, 0, 0); \
      } \
      __builtin_amdgcn_s_setprio(0); \
    } \
    WAIT_STMT; \
    __builtin_amdgcn_s_barrier(); \
    __builtin_amdgcn_sched_barrier(0); \
  } while (0)

__global__ __launch_bounds__(512, 4) void flash_attn(const u16* __restrict__ Q,
                                                     const u16* __restrict__ K,
                                                     const u16* __restrict__ Vt,
                                                     u16* __restrict__ O) {
    __shared__ u16 lds_all[16384];           // 32 KB: K/V dbuf 2x16KB
    int tid = threadIdx.x, lane = tid & 63, wid = tid >> 6;
    int l15 = lane & 15, quad = lane >> 4;
    int sw = l15 & 7;
    int h = blockIdx.y;
    int q0 = blockIdx.x * 256 + wid * 32;
    const u16* Qh = Q + (size_t)h * N_TOK * DHEAD;
    const u16* Kh = K + (size_t)h * N_TOK * DHEAD;
    const u16* Vh = Vt + (size_t)h * DHEAD * N_TOK;

    f32x4 zero4 = {0.f, 0.f, 0.f, 0.f};
    bf16x8 ones;
#pragma unroll
    for (int i = 0; i < 8; ++i) ones[i] = (short)0x3F80;  // bf16 1.0

    // Q fragments (B operand): B[n=q=l15][k=dhead]
    bf16x8 aq[2][2];
#pragma unroll
    for (int mtQ = 0; mtQ < 2; ++mtQ)
#pragma unroll
        for (int kc = 0; kc < 2; ++kc)
            aq[mtQ][kc] = *(const bf16x8*)&Qh[(size_t)(q0 + mtQ * 16 + l15) * DHEAD + kc * 32 + quad * 8];

    f32x4 o[2][4], lacc[2];
#pragma unroll
    for (int mtQ = 0; mtQ < 2; ++mtQ) {
#pragma unroll
        for (int dt = 0; dt < 4; ++dt) o[mtQ][dt] = zero4;
        lacc[mtQ] = zero4;
    }

    // staging: wave stages K rows [wid*8, wid*8+8) and V rows (d) same range
    int rowoff = lane >> 3;                      // 0..7
    int krow = wid * 8 + rowoff;                 // 0..63
    int kbase = wid * 512;                       // u16: wid*8 rows * 64
    int csw = ((lane & 7) ^ rowoff) * 8;         // swizzled source column (u16)

    // prologue: tiles 0,1 -> bufs 0,1 (4 loads); wait tile0 (2 newest remain)
    FA_STAGE(0, 0);
    FA_STAGE(1, 64);
    VM2;
    __builtin_amdgcn_s_barrier();
    __builtin_amdgcn_sched_barrier(0);

    for (int t = 0; t < 62; t += 2) {
        FA_TILE(0, FA_STAGE(0, (t + 2) * 64), VM2);
        FA_TILE(1, FA_STAGE(1, (t + 3) * 64), VM2);
    }
    FA_TILE(0, NOPS, VM0);        // tile 62; drain tile-63 loads
    FA_TILE(1, NOPS, NOPS);       // tile 63; nothing in flight

    // epilogue: transpose O^T -> O via per-wave LDS scratch, then coalesced write
    __syncthreads();
    u16* scratch = lds_all + wid * 2048;     // [q 32][d 64] per wave (4 KB)
#pragma unroll
    for (int mtQ = 0; mtQ < 2; ++mtQ) {
        float rl = 1.f / lacc[mtQ][0];
#pragma unroll
        for (int dt = 0; dt < 4; ++dt) {
            uint2 ov;
            ov.x = pk2bf(o[mtQ][dt][0] * rl, o[mtQ][dt][1] * rl);
            ov.y = pk2bf(o[mtQ][dt][2] * rl, o[mtQ][dt][3] * rl);
            *(uint2*)&scratch[(mtQ * 16 + l15) * 64 + dt * 16 + quad * 4] = ov;
        }
    }
#pragma unroll
    for (int p = 0; p < 4; ++p) {
        int q_local = p * 8 + (lane >> 3);
        int dcol = (lane & 7) * 8;
        bf16x8 v = *(const bf16x8*)&scratch[q_local * 64 + dcol];
        *(bf16x8*)&O[(size_t)(q0 + q_local) * INNER + h * 64 + dcol] = v;
    }
}

extern "C" void kernel_launch(void* const* d_in, const int* in_sizes, int n_in,
                              void* d_out, int out_size, void* d_ws, size_t ws_size,
                              hipStream_t stream) {
    const float* x     = (const float*)d_in[0];
    const float* pe    = (const float*)d_in[1];
    const float* w_qkv = (const float*)d_in[2];
    const float* w_out = (const float*)d_in[3];
    const float* ln_g  = (const float*)d_in[4];
    const float* ln_b  = (const float*)d_in[5];
    float* out = (float*)d_out;

    char* ws = (char*)d_ws;
    u16* xn  = (u16*)ws;  ws += (size_t)N_TOK * DMODEL * 2;
    u16* wq  = (u16*)ws;  ws += (size_t)3 * INNER * DMODEL * 2;
    u16* wo  = (u16*)ws;  ws += (size_t)DMODEL * INNER * 2;
    u16* qkv = (u16*)ws;  ws += (size_t)N_TOK * DMODEL * 2;
    u16* Qr  = (u16*)ws;  ws += (size_t)NH * N_TOK * DHEAD * 2;
    u16* Kr  = (u16*)ws;  ws += (size_t)NH * N_TOK * DHEAD * 2;
    u16* Vt  = (u16*)ws;  ws += (size_t)NH * DHEAD * N_TOK * 2;
    u16* Ob  = (u16*)ws;  ws += (size_t)N_TOK * INNER * 2;

    prep<<<4096 + 2048 + 512, 256, 0, stream>>>(x, ln_g, ln_b, xn, w_qkv, wq, w_out, wo);
    gemm256<1><<<dim3((N_TOK / 256) * (DMODEL / 256)), 512, 0, stream>>>(xn, wq, qkv, N_TOK, DMODEL, DMODEL);
    rope_vt<<<4096 + 1024, 256, 0, stream>>>(qkv, pe, Qr, Kr, Vt);
    flash_attn<<<dim3(N_TOK / 256, NH), 512, 0, stream>>>(Qr, Kr, Vt, Ob);
    gemm256<0><<<dim3((N_TOK / 256) * (DMODEL / 256)), 512, 0, stream>>>(Ob, wo, out, N_TOK, DMODEL, INNER);
}

// Round 7
// 352.131 us; speedup vs baseline: 1.7618x; 1.7618x over previous
//
#include <hip/hip_runtime.h>
#include <hip/hip_bf16.h>

typedef unsigned short u16;
typedef __attribute__((ext_vector_type(8))) short bf16x8;
typedef __attribute__((ext_vector_type(4))) float f32x4;

#define N_TOK 4096
#define DMODEL 3072
#define NH 16
#define DHEAD 64
#define INNER 1024
#define SCALE_LOG2E 0.18033688011112042f  /* (1/8) * log2(e) */

__device__ __forceinline__ u16 f2bf(float f) {
    union { float f; unsigned u; } un; un.f = f;
    unsigned r = un.u + 0x7fffu + ((un.u >> 16) & 1u);
    return (u16)(r >> 16);
}
__device__ __forceinline__ float bf2f(u16 u) {
    union { unsigned u; float f; } x; x.u = ((unsigned)u) << 16; return x.f;
}
// pack two f32 -> two bf16 (round-half-up) in 3 VALU ops; a -> low 16
__device__ __forceinline__ unsigned pk2bf(float a, float b) {
    union { float f; unsigned u; } ua, ub; ua.f = a; ub.f = b;
    return __builtin_amdgcn_perm(ub.u + 0x8000u, ua.u + 0x8000u, 0x07060302u);
}
__device__ __forceinline__ void load_lds16(const u16* g, u16* l) {
    __builtin_amdgcn_global_load_lds(
        (const __attribute__((address_space(1))) unsigned int*)g,
        (__attribute__((address_space(3))) unsigned int*)l, 16, 0, 0);
}

// Build PV B-operand in-register from packed exp2(S^T) words.
// Inputs: u0,u1 = key pairs (4q+0,1)/(4q+2,3) of lower 16 keys (s[lo]);
//         w0,w1 = same for upper 16 keys (s[hi]).
// Output: lane (l15,quad) holds keys [8*quad, 8*quad+8) for col q=l15.
// swap32: new0={old0.lo,old1.lo}; swap16: new0=[o0@g0,o1@g0,o0@g2,o1@g2].
__device__ __forceinline__ bf16x8 build_bp(unsigned u0, unsigned u1,
                                           unsigned w0, unsigned w1) {
    auto a = __builtin_amdgcn_permlane32_swap(u0, w0, false, false);
    auto b = __builtin_amdgcn_permlane16_swap(a[0], a[1], false, false);
    auto c = __builtin_amdgcn_permlane32_swap(u1, w1, false, false);
    auto d = __builtin_amdgcn_permlane16_swap(c[0], c[1], false, false);
    union { unsigned w[4]; bf16x8 v; } r;
    r.w[0] = b[0]; r.w[1] = d[0]; r.w[2] = b[1]; r.w[3] = d[1];
    return r.v;
}

// ------- Fused prep: LN rows (blocks 0..4095), wq cvt (4096..6143), --------
// ------- wo cvt (6144..6655). --------
__global__ __launch_bounds__(256) void prep(const float* __restrict__ x,
                                            const float* __restrict__ g,
                                            const float* __restrict__ b,
                                            u16* __restrict__ xn,
                                            const float* __restrict__ w_qkv,
                                            u16* __restrict__ wq,
                                            const float* __restrict__ w_out,
                                            u16* __restrict__ wo) {
    int bid = blockIdx.x;
    int tid = threadIdx.x;
    if (bid < 4096) {
        int row = bid;
        const float4* xr = (const float4*)(x + (size_t)row * DMODEL);
        float4 v[3];
        float s = 0.f, ss = 0.f;
#pragma unroll
        for (int i = 0; i < 3; ++i) {
            v[i] = xr[i * 256 + tid];
            s  += v[i].x + v[i].y + v[i].z + v[i].w;
            ss += v[i].x * v[i].x + v[i].y * v[i].y + v[i].z * v[i].z + v[i].w * v[i].w;
        }
#pragma unroll
        for (int off = 32; off; off >>= 1) {
            s  += __shfl_xor(s, off);
            ss += __shfl_xor(ss, off);
        }
        __shared__ float red[8];
        int wid = tid >> 6, lane = tid & 63;
        if (lane == 0) { red[wid] = s; red[wid + 4] = ss; }
        __syncthreads();
        s  = red[0] + red[1] + red[2] + red[3];
        ss = red[4] + red[5] + red[6] + red[7];
        float mean = s * (1.f / DMODEL);
        float var  = ss * (1.f / DMODEL) - mean * mean;
        float rstd = rsqrtf(var + 1e-5f);
        ushort4* orow = (ushort4*)(xn + (size_t)row * DMODEL);
#pragma unroll
        for (int i = 0; i < 3; ++i) {
            float4 gg = ((const float4*)g)[i * 256 + tid];
            float4 bb = ((const float4*)b)[i * 256 + tid];
            ushort4 o;
            o.x = f2bf((v[i].x - mean) * rstd * gg.x + bb.x);
            o.y = f2bf((v[i].y - mean) * rstd * gg.y + bb.y);
            o.z = f2bf((v[i].z - mean) * rstd * gg.z + bb.z);
            o.w = f2bf((v[i].w - mean) * rstd * gg.w + bb.w);
            orow[i * 256 + tid] = o;
        }
    } else if (bid < 4096 + 2048) {
        const int n4 = 3 * INNER * DMODEL / 4;
        for (int i = (bid - 4096) * 256 + tid; i < n4; i += 2048 * 256) {
            float4 v = ((const float4*)w_qkv)[i];
            ushort4 o;
            o.x = f2bf(v.x); o.y = f2bf(v.y); o.z = f2bf(v.z); o.w = f2bf(v.w);
            ((ushort4*)wq)[i] = o;
        }
    } else {
        const int n4 = DMODEL * INNER / 4;
        for (int i = (bid - 6144) * 256 + tid; i < n4; i += 512 * 256) {
            float4 v = ((const float4*)w_out)[i];
            ushort4 o;
            o.x = f2bf(v.x); o.y = f2bf(v.y); o.z = f2bf(v.z); o.w = f2bf(v.w);
            ((ushort4*)wo)[i] = o;
        }
    }
}

// ============ GEMM 256x256 8-phase (T2+T3+T4+T5), C = A * B^T ============
// (unchanged — verified R2-R6; control)

#define VM6 asm volatile("s_waitcnt vmcnt(6)" ::: "memory")
#define VM4 asm volatile("s_waitcnt vmcnt(4)" ::: "memory")
#define VM2 asm volatile("s_waitcnt vmcnt(2)" ::: "memory")
#define VM0 asm volatile("s_waitcnt vmcnt(0)" ::: "memory")
#define LGK8 asm volatile("s_waitcnt lgkmcnt(8)" ::: "memory")
#define NOPS ((void)0)

#define ST_A(d, h, t) do { \
    load_lds16(pA##h##0 + (size_t)(t) * 64, &lds[(d) * 16384 + (h) * 8192 + dq]); \
    load_lds16(pA##h##1 + (size_t)(t) * 64, &lds[(d) * 16384 + (h) * 8192 + dq + 512]); \
  } while (0)
#define ST_B(d, h, t) do { \
    load_lds16(pB##h##0 + (size_t)(t) * 64, &lds[32768 + (d) * 16384 + (h) * 8192 + dq]); \
    load_lds16(pB##h##1 + (size_t)(t) * 64, &lds[32768 + (d) * 16384 + (h) * 8192 + dq + 512]); \
  } while (0)

#define PHASE(d, p, STAGE, PRE, POST) do { \
    bf16x8 afr[2][2]; \
    if ((p) == 0) { \
      _Pragma("unroll") for (int nf = 0; nf < 4; ++nf) { \
        bfr[nf][0] = *(const bf16x8*)&lds[(d) * 16384 + baseB + nf * 1024 + c0]; \
        bfr[nf][1] = *(const bf16x8*)&lds[(d) * 16384 + baseB + nf * 1024 + c1]; \
      } \
    } \
    _Pragma("unroll") for (int mfl = 0; mfl < 2; ++mfl) { \
      afr[mfl][0] = *(const bf16x8*)&lds[(d) * 16384 + (p) * 4096 + mfl * 1024 + baseA + c0]; \
      afr[mfl][1] = *(const bf16x8*)&lds[(d) * 16384 + (p) * 4096 + mfl * 1024 + baseA + c1]; \
    } \
    STAGE; \
    PRE; \
    __builtin_amdgcn_s_barrier(); \
    asm volatile("s_waitcnt lgkmcnt(0)" ::: "memory"); \
    __builtin_amdgcn_sched_barrier(0); \
    __builtin_amdgcn_s_setprio(1); \
    _Pragma("unroll") for (int mfl = 0; mfl < 2; ++mfl) \
      _Pragma("unroll") for (int nf = 0; nf < 4; ++nf) { \
        acc[(p) * 2 + mfl][nf] = __builtin_amdgcn_mfma_f32_16x16x32_bf16(afr[mfl][0], bfr[nf][0], acc[(p) * 2 + mfl][nf], 0, 0, 0); \
        acc[(p) * 2 + mfl][nf] = __builtin_amdgcn_mfma_f32_16x16x32_bf16(afr[mfl][1], bfr[nf][1], acc[(p) * 2 + mfl][nf], 0, 0, 0); \
      } \
    __builtin_amdgcn_s_setprio(0); \
    POST; \
    __builtin_amdgcn_s_barrier(); \
  } while (0)

template <int CBF16>
__global__ __launch_bounds__(512, 2) void gemm256(const u16* __restrict__ A,
                                                  const u16* __restrict__ B,
                                                  void* __restrict__ C,
                                                  int M, int Nn, int K) {
    __shared__ u16 lds[65536];   // A: [2][256][64] @0 ; B: same @32768 (128 KiB)
    const int tid = threadIdx.x;
    const int lane = tid & 63, wid = tid >> 6;
    const int wm = wid >> 2, wn = wid & 3;
    const int l15 = lane & 15, quad = lane >> 4;
    const int sw = l15 & 7;

    // XCD-aware bijective swizzle (gridDim.x % 8 == 0)
    int nbx = Nn >> 8;
    int cpx = gridDim.x >> 3;
    int wg = (blockIdx.x & 7) * cpx + (blockIdx.x >> 3);
    int m0 = (wg / nbx) << 8, n0 = (wg % nbx) << 8;

    // per-thread ds_read bases (u16 units) and swizzled chunk offsets
    const int baseA = wm * 2048 + l15 * 64;
    const int baseB = 32768 + wn * 4096 + l15 * 64;
    const int c0 = (quad ^ sw) * 8;
    const int c1 = ((4 + quad) ^ sw) * 8;
    const int dq = wid * 1024;                 // stage LDS base (j adds 512)

    // stage source pointers: LDS row ell -> global row, pre-swizzled col
    const u16 *pA00, *pA01, *pA10, *pA11, *pB00, *pB01, *pB10, *pB11;
    {
        int scol = ((lane & 7) ^ (lane >> 3)) * 8;
#define MKSRC(h, j, PA, PB) { \
        int ell = (h) * 128 + (wid * 2 + (j)) * 8 + (lane >> 3); \
        int g = ell >> 6, wmh = (ell >> 5) & 1, r = ell & 31; \
        PA = A + (size_t)(m0 + wmh * 128 + g * 32 + r) * K + scol; \
        PB = B + (size_t)(n0 + ell) * K + scol; }
        MKSRC(0, 0, pA00, pB00) MKSRC(0, 1, pA01, pB01)
        MKSRC(1, 0, pA10, pB10) MKSRC(1, 1, pA11, pB11)
#undef MKSRC
    }

    f32x4 acc[8][4];
    f32x4 zero4 = {0.f, 0.f, 0.f, 0.f};
#pragma unroll
    for (int i = 0; i < 8; ++i)
#pragma unroll
        for (int j = 0; j < 4; ++j) acc[i][j] = zero4;
    bf16x8 bfr[4][2];

    // prologue: tile0 (4 halves) -> buf0, tile1 (B0,B1,A0) -> buf1
    ST_B(0, 0, 0); ST_B(0, 1, 0); ST_A(0, 0, 0); ST_A(0, 1, 0);
    ST_B(1, 0, 1); ST_B(1, 1, 1); ST_A(1, 0, 1);
    VM6;                                   // tile0 landed; 3 halves in flight
    __builtin_amdgcn_s_barrier();

    const int NIT = (K >> 7) - 1;          // T/2 - 1 iterations
    for (int i = 0; i < NIT; ++i) {
        int t = 2 * i;
        PHASE(0, 0, ST_A(1, 1, t + 1), LGK8, NOPS);
        PHASE(0, 1, ST_B(0, 0, t + 2), NOPS, NOPS);
        PHASE(0, 2, ST_B(0, 1, t + 2), NOPS, NOPS);
        PHASE(0, 3, ST_A(0, 0, t + 2), NOPS, VM6);
        PHASE(1, 0, ST_A(0, 1, t + 2), LGK8, NOPS);
        PHASE(1, 1, ST_B(1, 0, t + 3), NOPS, NOPS);
        PHASE(1, 2, ST_B(1, 1, t + 3), NOPS, NOPS);
        PHASE(1, 3, ST_A(1, 0, t + 3), NOPS, VM6);
    }
    {   // epilogue: tiles T-2 (buf0), T-1 (buf1); only (T-1).A1 left to stage
        int T = K >> 6;
        PHASE(0, 0, ST_A(1, 1, T - 1), LGK8, NOPS);
        PHASE(0, 1, NOPS, NOPS, NOPS);
        PHASE(0, 2, NOPS, NOPS, NOPS);
        PHASE(0, 3, NOPS, NOPS, VM0);
        PHASE(1, 0, NOPS, LGK8, NOPS);
        PHASE(1, 1, NOPS, NOPS, NOPS);
        PHASE(1, 2, NOPS, NOPS, NOPS);
        PHASE(1, 3, NOPS, NOPS, NOPS);
    }

    // C write: rr = m0 + wm*128 + mf*16 + quad*4 + r ; cc = n0 + wn*64 + nf*16 + l15
#pragma unroll
    for (int mf = 0; mf < 8; ++mf)
#pragma unroll
        for (int nf = 0; nf < 4; ++nf)
#pragma unroll
            for (int r = 0; r < 4; ++r) {
                int rr = m0 + wm * 128 + mf * 16 + quad * 4 + r;
                int cc = n0 + wn * 64 + nf * 16 + l15;
                if (CBF16)
                    ((u16*)C)[(size_t)rr * Nn + cc] = f2bf(acc[mf][nf][r]);
                else
                    ((float*)C)[(size_t)rr * Nn + cc] = acc[mf][nf][r];
            }
}

// ------- Fused RoPE (blocks 0..4095) + V transpose (4096..5119) -----------
__global__ __launch_bounds__(256) void rope_vt(const u16* __restrict__ qkv,
                                               const float* __restrict__ pe,
                                               u16* __restrict__ Qr,
                                               u16* __restrict__ Kr,
                                               u16* __restrict__ Vt) {
    int bid = blockIdx.x;
    int tid = threadIdx.x;
    if (bid < 4096) {
        int n = bid;
        const u16* qrow = qkv + (size_t)n * DMODEL;
        const float4* pen = (const float4*)(pe + (size_t)n * 128);
#pragma unroll
        for (int it = 0; it < 2; ++it) {
            int p = it * 256 + tid;      // pair index 0..511
            int h = p >> 5, i = p & 31;
            float4 w = pen[i];
            size_t obase = ((size_t)h * N_TOK + n) * DHEAD + 2 * i;
            unsigned qq = *(const unsigned*)&qrow[h * 64 + 2 * i];
            float q0 = bf2f((u16)qq), q1 = bf2f((u16)(qq >> 16));
            *(unsigned*)&Qr[obase] = pk2bf((w.x * q0 + w.y * q1) * SCALE_LOG2E,
                                           (w.z * q0 + w.w * q1) * SCALE_LOG2E);
            unsigned kk = *(const unsigned*)&qrow[INNER + h * 64 + 2 * i];
            float k0 = bf2f((u16)kk), k1 = bf2f((u16)(kk >> 16));
            *(unsigned*)&Kr[obase] = pk2bf(w.x * k0 + w.y * k1, w.z * k0 + w.w * k1);
        }
    } else {
        __shared__ u16 t[64][65];
        int tb = bid - 4096;
        int n0 = (tb & 63) * 64;
        int h = tb >> 6;
#pragma unroll
        for (int it = 0; it < 4; ++it) {
            int nr = it * 16 + (tid >> 4);
            int dc = (tid & 15) * 4;
            ushort4 v = *(const ushort4*)&qkv[(size_t)(n0 + nr) * DMODEL + 2 * INNER + h * 64 + dc];
            t[dc + 0][nr] = v.x; t[dc + 1][nr] = v.y; t[dc + 2][nr] = v.z; t[dc + 3][nr] = v.w;
        }
        __syncthreads();
#pragma unroll
        for (int it = 0; it < 4; ++it) {
            int dr = it * 16 + (tid >> 4);
            int nc = (tid & 15) * 4;
            ushort4 v;
            v.x = t[dr][nc]; v.y = t[dr][nc + 1]; v.z = t[dr][nc + 2]; v.w = t[dr][nc + 3];
            *(ushort4*)&Vt[((size_t)h * 64 + dr) * N_TOK + n0 + nc] = v;
        }
    }
}

// ---------------- Flash attention: 8 waves x 32 q-rows (QBLK 256) ---------
// R6 geometry, R7 fix: __launch_bounds__(512, 2). R6's (512,4) capped the
// allocator at 64 VGPR (4x512thr blocks/CU = 8 waves/SIMD) -> massive
// scratch spill (WRITE_SIZE 803 MB, 3.6x slowdown). (512,2) = 128-VGPR cap;
// per-thread state ~92-110 (R3/R4 measured 92 for same per-wave compute).

#define FA_STAGE(d, kt) do { \
    load_lds16(&Kh[(size_t)((kt) + krow) * DHEAD + csw], &lds_all[(d) * 8192 + kbase]); \
    load_lds16(&Vh[(size_t)krow * N_TOK + (kt) + csw], &lds_all[(d) * 8192 + 4096 + kbase]); \
  } while (0)

#define FA_TILE(d, STAGE_STMT, WAIT_STMT) do { \
    bf16x8 bk[4][2], av[4][2]; \
    _Pragma("unroll") for (int tt = 0; tt < 4; ++tt) \
      _Pragma("unroll") for (int kc = 0; kc < 2; ++kc) { \
        int off = (d) * 8192 + (tt * 16 + l15) * 64 + (((kc * 4 + quad) ^ sw) * 8); \
        bk[tt][kc] = *(const bf16x8*)&lds_all[off]; \
        av[tt][kc] = *(const bf16x8*)&lds_all[off + 4096]; \
      } \
    asm volatile("s_waitcnt lgkmcnt(0)" ::: "memory"); \
    __builtin_amdgcn_sched_barrier(0); \
    __builtin_amdgcn_s_barrier(); \
    __builtin_amdgcn_sched_barrier(0); \
    STAGE_STMT; \
    _Pragma("unroll") for (int mtQ = 0; mtQ < 2; ++mtQ) { \
      f32x4 s[4]; \
      __builtin_amdgcn_s_setprio(1); \
      _Pragma("unroll") for (int ntK = 0; ntK < 4; ++ntK) { \
        f32x4 t0 = __builtin_amdgcn_mfma_f32_16x16x32_bf16(bk[ntK][0], aq[mtQ][0], zero4, 0, 0, 0); \
        s[ntK] = __builtin_amdgcn_mfma_f32_16x16x32_bf16(bk[ntK][1], aq[mtQ][1], t0, 0, 0, 0); \
      } \
      __builtin_amdgcn_s_setprio(0); \
      unsigned pw[4][2]; \
      _Pragma("unroll") for (int ntK = 0; ntK < 4; ++ntK) { \
        pw[ntK][0] = pk2bf(__builtin_amdgcn_exp2f(s[ntK][0]), __builtin_amdgcn_exp2f(s[ntK][1])); \
        pw[ntK][1] = pk2bf(__builtin_amdgcn_exp2f(s[ntK][2]), __builtin_amdgcn_exp2f(s[ntK][3])); \
      } \
      bf16x8 bp0 = build_bp(pw[0][0], pw[0][1], pw[1][0], pw[1][1]); \
      bf16x8 bp1 = build_bp(pw[2][0], pw[2][1], pw[3][0], pw[3][1]); \
      __builtin_amdgcn_s_setprio(1); \
      lacc[mtQ] = __builtin_amdgcn_mfma_f32_16x16x32_bf16(ones, bp0, lacc[mtQ], 0, 0, 0); \
      lacc[mtQ] = __builtin_amdgcn_mfma_f32_16x16x32_bf16(ones, bp1, lacc[mtQ], 0, 0, 0); \
      _Pragma("unroll") for (int dt = 0; dt < 4; ++dt) { \
        o[mtQ][dt] = __builtin_amdgcn_mfma_f32_16x16x32_bf16(av[dt][0], bp0, o[mtQ][dt], 0, 0, 0); \
        o[mtQ][dt] = __builtin_amdgcn_mfma_f32_16x16x32_bf16(av[dt][1], bp1, o[mtQ][dt], 0, 0, 0); \
      } \
      __builtin_amdgcn_s_setprio(0); \
    } \
    WAIT_STMT; \
    __builtin_amdgcn_s_barrier(); \
    __builtin_amdgcn_sched_barrier(0); \
  } while (0)

__global__ __launch_bounds__(512, 2) void flash_attn(const u16* __restrict__ Q,
                                                     const u16* __restrict__ K,
                                                     const u16* __restrict__ Vt,
                                                     u16* __restrict__ O) {
    __shared__ u16 lds_all[16384];           // 32 KB: K/V dbuf 2x16KB
    int tid = threadIdx.x, lane = tid & 63, wid = tid >> 6;
    int l15 = lane & 15, quad = lane >> 4;
    int sw = l15 & 7;
    int h = blockIdx.y;
    int q0 = blockIdx.x * 256 + wid * 32;
    const u16* Qh = Q + (size_t)h * N_TOK * DHEAD;
    const u16* Kh = K + (size_t)h * N_TOK * DHEAD;
    const u16* Vh = Vt + (size_t)h * DHEAD * N_TOK;

    f32x4 zero4 = {0.f, 0.f, 0.f, 0.f};
    bf16x8 ones;
#pragma unroll
    for (int i = 0; i < 8; ++i) ones[i] = (short)0x3F80;  // bf16 1.0

    // Q fragments (B operand): B[n=q=l15][k=dhead]
    bf16x8 aq[2][2];
#pragma unroll
    for (int mtQ = 0; mtQ < 2; ++mtQ)
#pragma unroll
        for (int kc = 0; kc < 2; ++kc)
            aq[mtQ][kc] = *(const bf16x8*)&Qh[(size_t)(q0 + mtQ * 16 + l15) * DHEAD + kc * 32 + quad * 8];

    f32x4 o[2][4], lacc[2];
#pragma unroll
    for (int mtQ = 0; mtQ < 2; ++mtQ) {
#pragma unroll
        for (int dt = 0; dt < 4; ++dt) o[mtQ][dt] = zero4;
        lacc[mtQ] = zero4;
    }

    // staging: wave stages K rows [wid*8, wid*8+8) and V rows (d) same range
    int rowoff = lane >> 3;                      // 0..7
    int krow = wid * 8 + rowoff;                 // 0..63
    int kbase = wid * 512;                       // u16: wid*8 rows * 64
    int csw = ((lane & 7) ^ rowoff) * 8;         // swizzled source column (u16)

    // prologue: tiles 0,1 -> bufs 0,1 (4 loads); wait tile0 (2 newest remain)
    FA_STAGE(0, 0);
    FA_STAGE(1, 64);
    VM2;
    __builtin_amdgcn_s_barrier();
    __builtin_amdgcn_sched_barrier(0);

    for (int t = 0; t < 62; t += 2) {
        FA_TILE(0, FA_STAGE(0, (t + 2) * 64), VM2);
        FA_TILE(1, FA_STAGE(1, (t + 3) * 64), VM2);
    }
    FA_TILE(0, NOPS, VM0);        // tile 62; drain tile-63 loads
    FA_TILE(1, NOPS, NOPS);       // tile 63; nothing in flight

    // epilogue: transpose O^T -> O via per-wave LDS scratch, then coalesced write
    __syncthreads();
    u16* scratch = lds_all + wid * 2048;     // [q 32][d 64] per wave (4 KB)
#pragma unroll
    for (int mtQ = 0; mtQ < 2; ++mtQ) {
        float rl = 1.f / lacc[mtQ][0];
#pragma unroll
        for (int dt = 0; dt < 4; ++dt) {
            uint2 ov;
            ov.x = pk2bf(o[mtQ][dt][0] * rl, o[mtQ][dt][1] * rl);
            ov.y = pk2bf(o[mtQ][dt][2] * rl, o[mtQ][dt][3] * rl);
            *(uint2*)&scratch[(mtQ * 16 + l15) * 64 + dt * 16 + quad * 4] = ov;
        }
    }
#pragma unroll
    for (int p = 0; p < 4; ++p) {
        int q_local = p * 8 + (lane >> 3);
        int dcol = (lane & 7) * 8;
        bf16x8 v = *(const bf16x8*)&scratch[q_local * 64 + dcol];
        *(bf16x8*)&O[(size_t)(q0 + q_local) * INNER + h * 64 + dcol] = v;
    }
}

extern "C" void kernel_launch(void* const* d_in, const int* in_sizes, int n_in,
                              void* d_out, int out_size, void* d_ws, size_t ws_size,
                              hipStream_t stream) {
    const float* x     = (const float*)d_in[0];
    const float* pe    = (const float*)d_in[1];
    const float* w_qkv = (const float*)d_in[2];
    const float* w_out = (const float*)d_in[3];
    const float* ln_g  = (const float*)d_in[4];
    const float* ln_b  = (const float*)d_in[5];
    float* out = (float*)d_out;

    char* ws = (char*)d_ws;
    u16* xn  = (u16*)ws;  ws += (size_t)N_TOK * DMODEL * 2;
    u16* wq  = (u16*)ws;  ws += (size_t)3 * INNER * DMODEL * 2;
    u16* wo  = (u16*)ws;  ws += (size_t)DMODEL * INNER * 2;
    u16* qkv = (u16*)ws;  ws += (size_t)N_TOK * DMODEL * 2;
    u16* Qr  = (u16*)ws;  ws += (size_t)NH * N_TOK * DHEAD * 2;
    u16* Kr  = (u16*)ws;  ws += (size_t)NH * N_TOK * DHEAD * 2;
    u16* Vt  = (u16*)ws;  ws += (size_t)NH * DHEAD * N_TOK * 2;
    u16* Ob  = (u16*)ws;  ws += (size_t)N_TOK * INNER * 2;

    prep<<<4096 + 2048 + 512, 256, 0, stream>>>(x, ln_g, ln_b, xn, w_qkv, wq, w_out, wo);
    gemm256<1><<<dim3((N_TOK / 256) * (DMODEL / 256)), 512, 0, stream>>>(xn, wq, qkv, N_TOK, DMODEL, DMODEL);
    rope_vt<<<4096 + 1024, 256, 0, stream>>>(qkv, pe, Qr, Kr, Vt);
    flash_attn<<<dim3(N_TOK / 256, NH), 512, 0, stream>>>(Qr, Kr, Vt, Ob);
    gemm256<0><<<dim3((N_TOK / 256) * (DMODEL / 256)), 512, 0, stream>>>(Ob, wo, out, N_TOK, DMODEL, INNER);
}

// Round 8
// 351.554 us; speedup vs baseline: 1.7647x; 1.0016x over previous
//
#include <hip/hip_runtime.h>
#include <hip/hip_bf16.h>

typedef unsigned short u16;
typedef __attribute__((ext_vector_type(8))) short bf16x8;
typedef __attribute__((ext_vector_type(4))) float f32x4;

#define N_TOK 4096
#define DMODEL 3072
#define NH 16
#define DHEAD 64
#define INNER 1024
#define SCALE_LOG2E 0.18033688011112042f  /* (1/8) * log2(e) */

__device__ __forceinline__ u16 f2bf(float f) {
    union { float f; unsigned u; } un; un.f = f;
    unsigned r = un.u + 0x7fffu + ((un.u >> 16) & 1u);
    return (u16)(r >> 16);
}
__device__ __forceinline__ float bf2f(u16 u) {
    union { unsigned u; float f; } x; x.u = ((unsigned)u) << 16; return x.f;
}
// pack two f32 -> two bf16 (round-half-up) in 3 VALU ops; a -> low 16
__device__ __forceinline__ unsigned pk2bf(float a, float b) {
    union { float f; unsigned u; } ua, ub; ua.f = a; ub.f = b;
    return __builtin_amdgcn_perm(ub.u + 0x8000u, ua.u + 0x8000u, 0x07060302u);
}
__device__ __forceinline__ void load_lds16(const u16* g, u16* l) {
    __builtin_amdgcn_global_load_lds(
        (const __attribute__((address_space(1))) unsigned int*)g,
        (__attribute__((address_space(3))) unsigned int*)l, 16, 0, 0);
}

// Build PV B-operand in-register from packed exp2(S^T) words.
// Output: lane (l15,quad) holds keys [8*quad, 8*quad+8) for col q=l15.
__device__ __forceinline__ bf16x8 build_bp(unsigned u0, unsigned u1,
                                           unsigned w0, unsigned w1) {
    auto a = __builtin_amdgcn_permlane32_swap(u0, w0, false, false);
    auto b = __builtin_amdgcn_permlane16_swap(a[0], a[1], false, false);
    auto c = __builtin_amdgcn_permlane32_swap(u1, w1, false, false);
    auto d = __builtin_amdgcn_permlane16_swap(c[0], c[1], false, false);
    union { unsigned w[4]; bf16x8 v; } r;
    r.w[0] = b[0]; r.w[1] = d[0]; r.w[2] = b[1]; r.w[3] = d[1];
    return r.v;
}

// ------- Fused prep: LN rows (blocks 0..4095), wq cvt (4096..6143), --------
// ------- wo cvt (6144..6655). --------
__global__ __launch_bounds__(256) void prep(const float* __restrict__ x,
                                            const float* __restrict__ g,
                                            const float* __restrict__ b,
                                            u16* __restrict__ xn,
                                            const float* __restrict__ w_qkv,
                                            u16* __restrict__ wq,
                                            const float* __restrict__ w_out,
                                            u16* __restrict__ wo) {
    int bid = blockIdx.x;
    int tid = threadIdx.x;
    if (bid < 4096) {
        int row = bid;
        const float4* xr = (const float4*)(x + (size_t)row * DMODEL);
        float4 v[3];
        float s = 0.f, ss = 0.f;
#pragma unroll
        for (int i = 0; i < 3; ++i) {
            v[i] = xr[i * 256 + tid];
            s  += v[i].x + v[i].y + v[i].z + v[i].w;
            ss += v[i].x * v[i].x + v[i].y * v[i].y + v[i].z * v[i].z + v[i].w * v[i].w;
        }
#pragma unroll
        for (int off = 32; off; off >>= 1) {
            s  += __shfl_xor(s, off);
            ss += __shfl_xor(ss, off);
        }
        __shared__ float red[8];
        int wid = tid >> 6, lane = tid & 63;
        if (lane == 0) { red[wid] = s; red[wid + 4] = ss; }
        __syncthreads();
        s  = red[0] + red[1] + red[2] + red[3];
        ss = red[4] + red[5] + red[6] + red[7];
        float mean = s * (1.f / DMODEL);
        float var  = ss * (1.f / DMODEL) - mean * mean;
        float rstd = rsqrtf(var + 1e-5f);
        ushort4* orow = (ushort4*)(xn + (size_t)row * DMODEL);
#pragma unroll
        for (int i = 0; i < 3; ++i) {
            float4 gg = ((const float4*)g)[i * 256 + tid];
            float4 bb = ((const float4*)b)[i * 256 + tid];
            ushort4 o;
            o.x = f2bf((v[i].x - mean) * rstd * gg.x + bb.x);
            o.y = f2bf((v[i].y - mean) * rstd * gg.y + bb.y);
            o.z = f2bf((v[i].z - mean) * rstd * gg.z + bb.z);
            o.w = f2bf((v[i].w - mean) * rstd * gg.w + bb.w);
            orow[i * 256 + tid] = o;
        }
    } else if (bid < 4096 + 2048) {
        const int n4 = 3 * INNER * DMODEL / 4;
        for (int i = (bid - 4096) * 256 + tid; i < n4; i += 2048 * 256) {
            float4 v = ((const float4*)w_qkv)[i];
            ushort4 o;
            o.x = f2bf(v.x); o.y = f2bf(v.y); o.z = f2bf(v.z); o.w = f2bf(v.w);
            ((ushort4*)wq)[i] = o;
        }
    } else {
        const int n4 = DMODEL * INNER / 4;
        for (int i = (bid - 6144) * 256 + tid; i < n4; i += 512 * 256) {
            float4 v = ((const float4*)w_out)[i];
            ushort4 o;
            o.x = f2bf(v.x); o.y = f2bf(v.y); o.z = f2bf(v.z); o.w = f2bf(v.w);
            ((ushort4*)wo)[i] = o;
        }
    }
}

// ============ GEMM 256x256 8-phase (T2+T3+T4+T5), C = A * B^T ============
// (unchanged — verified R2-R7; control)

#define VM6 asm volatile("s_waitcnt vmcnt(6)" ::: "memory")
#define VM2 asm volatile("s_waitcnt vmcnt(2)" ::: "memory")
#define VM0 asm volatile("s_waitcnt vmcnt(0)" ::: "memory")
#define LGK8 asm volatile("s_waitcnt lgkmcnt(8)" ::: "memory")
#define NOPS ((void)0)

#define ST_A(d, h, t) do { \
    load_lds16(pA##h##0 + (size_t)(t) * 64, &lds[(d) * 16384 + (h) * 8192 + dq]); \
    load_lds16(pA##h##1 + (size_t)(t) * 64, &lds[(d) * 16384 + (h) * 8192 + dq + 512]); \
  } while (0)
#define ST_B(d, h, t) do { \
    load_lds16(pB##h##0 + (size_t)(t) * 64, &lds[32768 + (d) * 16384 + (h) * 8192 + dq]); \
    load_lds16(pB##h##1 + (size_t)(t) * 64, &lds[32768 + (d) * 16384 + (h) * 8192 + dq + 512]); \
  } while (0)

#define PHASE(d, p, STAGE, PRE, POST) do { \
    bf16x8 afr[2][2]; \
    if ((p) == 0) { \
      _Pragma("unroll") for (int nf = 0; nf < 4; ++nf) { \
        bfr[nf][0] = *(const bf16x8*)&lds[(d) * 16384 + baseB + nf * 1024 + c0]; \
        bfr[nf][1] = *(const bf16x8*)&lds[(d) * 16384 + baseB + nf * 1024 + c1]; \
      } \
    } \
    _Pragma("unroll") for (int mfl = 0; mfl < 2; ++mfl) { \
      afr[mfl][0] = *(const bf16x8*)&lds[(d) * 16384 + (p) * 4096 + mfl * 1024 + baseA + c0]; \
      afr[mfl][1] = *(const bf16x8*)&lds[(d) * 16384 + (p) * 4096 + mfl * 1024 + baseA + c1]; \
    } \
    STAGE; \
    PRE; \
    __builtin_amdgcn_s_barrier(); \
    asm volatile("s_waitcnt lgkmcnt(0)" ::: "memory"); \
    __builtin_amdgcn_sched_barrier(0); \
    __builtin_amdgcn_s_setprio(1); \
    _Pragma("unroll") for (int mfl = 0; mfl < 2; ++mfl) \
      _Pragma("unroll") for (int nf = 0; nf < 4; ++nf) { \
        acc[(p) * 2 + mfl][nf] = __builtin_amdgcn_mfma_f32_16x16x32_bf16(afr[mfl][0], bfr[nf][0], acc[(p) * 2 + mfl][nf], 0, 0, 0); \
        acc[(p) * 2 + mfl][nf] = __builtin_amdgcn_mfma_f32_16x16x32_bf16(afr[mfl][1], bfr[nf][1], acc[(p) * 2 + mfl][nf], 0, 0, 0); \
      } \
    __builtin_amdgcn_s_setprio(0); \
    POST; \
    __builtin_amdgcn_s_barrier(); \
  } while (0)

template <int CBF16>
__global__ __launch_bounds__(512, 2) void gemm256(const u16* __restrict__ A,
                                                  const u16* __restrict__ B,
                                                  void* __restrict__ C,
                                                  int M, int Nn, int K) {
    __shared__ u16 lds[65536];   // A: [2][256][64] @0 ; B: same @32768 (128 KiB)
    const int tid = threadIdx.x;
    const int lane = tid & 63, wid = tid >> 6;
    const int wm = wid >> 2, wn = wid & 3;
    const int l15 = lane & 15, quad = lane >> 4;
    const int sw = l15 & 7;

    // XCD-aware bijective swizzle (gridDim.x % 8 == 0)
    int nbx = Nn >> 8;
    int cpx = gridDim.x >> 3;
    int wg = (blockIdx.x & 7) * cpx + (blockIdx.x >> 3);
    int m0 = (wg / nbx) << 8, n0 = (wg % nbx) << 8;

    // per-thread ds_read bases (u16 units) and swizzled chunk offsets
    const int baseA = wm * 2048 + l15 * 64;
    const int baseB = 32768 + wn * 4096 + l15 * 64;
    const int c0 = (quad ^ sw) * 8;
    const int c1 = ((4 + quad) ^ sw) * 8;
    const int dq = wid * 1024;                 // stage LDS base (j adds 512)

    // stage source pointers: LDS row ell -> global row, pre-swizzled col
    const u16 *pA00, *pA01, *pA10, *pA11, *pB00, *pB01, *pB10, *pB11;
    {
        int scol = ((lane & 7) ^ (lane >> 3)) * 8;
#define MKSRC(h, j, PA, PB) { \
        int ell = (h) * 128 + (wid * 2 + (j)) * 8 + (lane >> 3); \
        int g = ell >> 6, wmh = (ell >> 5) & 1, r = ell & 31; \
        PA = A + (size_t)(m0 + wmh * 128 + g * 32 + r) * K + scol; \
        PB = B + (size_t)(n0 + ell) * K + scol; }
        MKSRC(0, 0, pA00, pB00) MKSRC(0, 1, pA01, pB01)
        MKSRC(1, 0, pA10, pB10) MKSRC(1, 1, pA11, pB11)
#undef MKSRC
    }

    f32x4 acc[8][4];
    f32x4 zero4 = {0.f, 0.f, 0.f, 0.f};
#pragma unroll
    for (int i = 0; i < 8; ++i)
#pragma unroll
        for (int j = 0; j < 4; ++j) acc[i][j] = zero4;
    bf16x8 bfr[4][2];

    // prologue: tile0 (4 halves) -> buf0, tile1 (B0,B1,A0) -> buf1
    ST_B(0, 0, 0); ST_B(0, 1, 0); ST_A(0, 0, 0); ST_A(0, 1, 0);
    ST_B(1, 0, 1); ST_B(1, 1, 1); ST_A(1, 0, 1);
    VM6;                                   // tile0 landed; 3 halves in flight
    __builtin_amdgcn_s_barrier();

    const int NIT = (K >> 7) - 1;          // T/2 - 1 iterations
    for (int i = 0; i < NIT; ++i) {
        int t = 2 * i;
        PHASE(0, 0, ST_A(1, 1, t + 1), LGK8, NOPS);
        PHASE(0, 1, ST_B(0, 0, t + 2), NOPS, NOPS);
        PHASE(0, 2, ST_B(0, 1, t + 2), NOPS, NOPS);
        PHASE(0, 3, ST_A(0, 0, t + 2), NOPS, VM6);
        PHASE(1, 0, ST_A(0, 1, t + 2), LGK8, NOPS);
        PHASE(1, 1, ST_B(1, 0, t + 3), NOPS, NOPS);
        PHASE(1, 2, ST_B(1, 1, t + 3), NOPS, NOPS);
        PHASE(1, 3, ST_A(1, 0, t + 3), NOPS, VM6);
    }
    {   // epilogue: tiles T-2 (buf0), T-1 (buf1); only (T-1).A1 left to stage
        int T = K >> 6;
        PHASE(0, 0, ST_A(1, 1, T - 1), LGK8, NOPS);
        PHASE(0, 1, NOPS, NOPS, NOPS);
        PHASE(0, 2, NOPS, NOPS, NOPS);
        PHASE(0, 3, NOPS, NOPS, VM0);
        PHASE(1, 0, NOPS, LGK8, NOPS);
        PHASE(1, 1, NOPS, NOPS, NOPS);
        PHASE(1, 2, NOPS, NOPS, NOPS);
        PHASE(1, 3, NOPS, NOPS, NOPS);
    }

    // C write: rr = m0 + wm*128 + mf*16 + quad*4 + r ; cc = n0 + wn*64 + nf*16 + l15
#pragma unroll
    for (int mf = 0; mf < 8; ++mf)
#pragma unroll
        for (int nf = 0; nf < 4; ++nf)
#pragma unroll
            for (int r = 0; r < 4; ++r) {
                int rr = m0 + wm * 128 + mf * 16 + quad * 4 + r;
                int cc = n0 + wn * 64 + nf * 16 + l15;
                if (CBF16)
                    ((u16*)C)[(size_t)rr * Nn + cc] = f2bf(acc[mf][nf][r]);
                else
                    ((float*)C)[(size_t)rr * Nn + cc] = acc[mf][nf][r];
            }
}

// ------- Fused RoPE (blocks 0..4095) + V transpose (4096..5119) -----------
__global__ __launch_bounds__(256) void rope_vt(const u16* __restrict__ qkv,
                                               const float* __restrict__ pe,
                                               u16* __restrict__ Qr,
                                               u16* __restrict__ Kr,
                                               u16* __restrict__ Vt) {
    int bid = blockIdx.x;
    int tid = threadIdx.x;
    if (bid < 4096) {
        int n = bid;
        const u16* qrow = qkv + (size_t)n * DMODEL;
        const float4* pen = (const float4*)(pe + (size_t)n * 128);
#pragma unroll
        for (int it = 0; it < 2; ++it) {
            int p = it * 256 + tid;      // pair index 0..511
            int h = p >> 5, i = p & 31;
            float4 w = pen[i];
            size_t obase = ((size_t)h * N_TOK + n) * DHEAD + 2 * i;
            unsigned qq = *(const unsigned*)&qrow[h * 64 + 2 * i];
            float q0 = bf2f((u16)qq), q1 = bf2f((u16)(qq >> 16));
            *(unsigned*)&Qr[obase] = pk2bf((w.x * q0 + w.y * q1) * SCALE_LOG2E,
                                           (w.z * q0 + w.w * q1) * SCALE_LOG2E);
            unsigned kk = *(const unsigned*)&qrow[INNER + h * 64 + 2 * i];
            float k0 = bf2f((u16)kk), k1 = bf2f((u16)(kk >> 16));
            *(unsigned*)&Kr[obase] = pk2bf(w.x * k0 + w.y * k1, w.z * k0 + w.w * k1);
        }
    } else {
        __shared__ u16 t[64][65];
        int tb = bid - 4096;
        int n0 = (tb & 63) * 64;
        int h = tb >> 6;
#pragma unroll
        for (int it = 0; it < 4; ++it) {
            int nr = it * 16 + (tid >> 4);
            int dc = (tid & 15) * 4;
            ushort4 v = *(const ushort4*)&qkv[(size_t)(n0 + nr) * DMODEL + 2 * INNER + h * 64 + dc];
            t[dc + 0][nr] = v.x; t[dc + 1][nr] = v.y; t[dc + 2][nr] = v.z; t[dc + 3][nr] = v.w;
        }
        __syncthreads();
#pragma unroll
        for (int it = 0; it < 4; ++it) {
            int dr = it * 16 + (tid >> 4);
            int nc = (tid & 15) * 4;
            ushort4 v;
            v.x = t[dr][nc]; v.y = t[dr][nc + 1]; v.z = t[dr][nc + 2]; v.w = t[dr][nc + 3];
            *(ushort4*)&Vt[((size_t)h * 64 + dr) * N_TOK + n0 + nc] = v;
        }
    }
}

// ---------------- Flash attention: 3-buffer rotation, split lgkm waits ----
// R8: the stage-into-read-buffer trick (R3-R7) forced lgkmcnt(0) on all 16
// ds_reads BEFORE compute — serializing ~1540 cyc/tile of CU-wide LDS
// service against MFMA+VALU (counters: Mfma 31% + VALU 41% alternating).
// Now: 3 x 16KB rotation (read buf[t%3], stage t+2 -> buf[(t+2)%3]);
// issue bk reads, av reads, stage; lgkm(8) -> QK+softmax (av in flight);
// lgkm(0) -> PV; vmcnt(2); ONE barrier per tile (was 2).
// Race audit: reads of buf X finish before each wave's mid-tile lgkm0,
// which precedes the end-of-tile barrier, which precedes any stage-issue
// targeting X (at t+1). Numerics identical to R7.

#define FA_STAGE3(dst, kt) do { \
    load_lds16(&Kh[(size_t)((kt) + krow) * DHEAD + csw], &lds_all[(dst) + kbase]); \
    load_lds16(&Vh[(size_t)krow * N_TOK + (kt) + csw], &lds_all[(dst) + 4096 + kbase]); \
  } while (0)

__global__ __launch_bounds__(512, 2) void flash_attn(const u16* __restrict__ Q,
                                                     const u16* __restrict__ K,
                                                     const u16* __restrict__ Vt,
                                                     u16* __restrict__ O) {
    __shared__ u16 lds_all[24576];           // 48 KB: 3 x 16KB K/V rotation
    int tid = threadIdx.x, lane = tid & 63, wid = tid >> 6;
    int l15 = lane & 15, quad = lane >> 4;
    int sw = l15 & 7;
    int h = blockIdx.y;
    int q0 = blockIdx.x * 256 + wid * 32;
    const u16* Qh = Q + (size_t)h * N_TOK * DHEAD;
    const u16* Kh = K + (size_t)h * N_TOK * DHEAD;
    const u16* Vh = Vt + (size_t)h * DHEAD * N_TOK;

    f32x4 zero4 = {0.f, 0.f, 0.f, 0.f};
    bf16x8 ones;
#pragma unroll
    for (int i = 0; i < 8; ++i) ones[i] = (short)0x3F80;  // bf16 1.0

    // Q fragments (B operand): B[n=q=l15][k=dhead]
    bf16x8 aq[2][2];
#pragma unroll
    for (int mtQ = 0; mtQ < 2; ++mtQ)
#pragma unroll
        for (int kc = 0; kc < 2; ++kc)
            aq[mtQ][kc] = *(const bf16x8*)&Qh[(size_t)(q0 + mtQ * 16 + l15) * DHEAD + kc * 32 + quad * 8];

    f32x4 o[2][4], lacc[2];
#pragma unroll
    for (int mtQ = 0; mtQ < 2; ++mtQ) {
#pragma unroll
        for (int dt = 0; dt < 4; ++dt) o[mtQ][dt] = zero4;
        lacc[mtQ] = zero4;
    }

    // staging: wave stages K rows [wid*8, wid*8+8) and V rows same range
    int rowoff = lane >> 3;                      // 0..7
    int krow = wid * 8 + rowoff;                 // 0..63
    int kbase = wid * 512;                       // u16: wid*8 rows * 64
    int csw = ((lane & 7) ^ rowoff) * 8;         // swizzled source column (u16)

    // prologue: tiles 0,1 -> bufs 0,1; wait tile0 (tile1's 2 loads in flight)
    FA_STAGE3(0, 0);
    FA_STAGE3(8192, 64);
    VM2;
    __builtin_amdgcn_s_barrier();
    __builtin_amdgcn_sched_barrier(0);

    int cur = 0;
    for (int t = 0; t < 64; ++t) {
        int stg = cur + 16384; if (stg >= 24576) stg -= 24576;  // (t+2)%3
        bf16x8 bk[4][2], av[4][2];
#pragma unroll
        for (int tt = 0; tt < 4; ++tt)
#pragma unroll
            for (int kc = 0; kc < 2; ++kc)
                bk[tt][kc] = *(const bf16x8*)&lds_all[cur + (tt * 16 + l15) * 64 + (((kc * 4 + quad) ^ sw) * 8)];
        __builtin_amdgcn_sched_barrier(0);
#pragma unroll
        for (int tt = 0; tt < 4; ++tt)
#pragma unroll
            for (int kc = 0; kc < 2; ++kc)
                av[tt][kc] = *(const bf16x8*)&lds_all[cur + 4096 + (tt * 16 + l15) * 64 + (((kc * 4 + quad) ^ sw) * 8)];
        __builtin_amdgcn_sched_barrier(0);
        if (t < 62) FA_STAGE3(stg, (t + 2) * 64);
        asm volatile("s_waitcnt lgkmcnt(8)" ::: "memory");   // bk ready; av in flight
        __builtin_amdgcn_sched_barrier(0);

        bf16x8 bp[2][2];
#pragma unroll
        for (int mtQ = 0; mtQ < 2; ++mtQ) {
            f32x4 s[4];
            __builtin_amdgcn_s_setprio(1);
#pragma unroll
            for (int ntK = 0; ntK < 4; ++ntK) {
                f32x4 t0 = __builtin_amdgcn_mfma_f32_16x16x32_bf16(bk[ntK][0], aq[mtQ][0], zero4, 0, 0, 0);
                s[ntK] = __builtin_amdgcn_mfma_f32_16x16x32_bf16(bk[ntK][1], aq[mtQ][1], t0, 0, 0, 0);
            }
            __builtin_amdgcn_s_setprio(0);
            unsigned pw[4][2];
#pragma unroll
            for (int ntK = 0; ntK < 4; ++ntK) {
                pw[ntK][0] = pk2bf(__builtin_amdgcn_exp2f(s[ntK][0]), __builtin_amdgcn_exp2f(s[ntK][1]));
                pw[ntK][1] = pk2bf(__builtin_amdgcn_exp2f(s[ntK][2]), __builtin_amdgcn_exp2f(s[ntK][3]));
            }
            bp[mtQ][0] = build_bp(pw[0][0], pw[0][1], pw[1][0], pw[1][1]);
            bp[mtQ][1] = build_bp(pw[2][0], pw[2][1], pw[3][0], pw[3][1]);
        }

        asm volatile("s_waitcnt lgkmcnt(0)" ::: "memory");   // av ready
        __builtin_amdgcn_sched_barrier(0);
        __builtin_amdgcn_s_setprio(1);
#pragma unroll
        for (int mtQ = 0; mtQ < 2; ++mtQ) {
            lacc[mtQ] = __builtin_amdgcn_mfma_f32_16x16x32_bf16(ones, bp[mtQ][0], lacc[mtQ], 0, 0, 0);
            lacc[mtQ] = __builtin_amdgcn_mfma_f32_16x16x32_bf16(ones, bp[mtQ][1], lacc[mtQ], 0, 0, 0);
#pragma unroll
            for (int dt = 0; dt < 4; ++dt) {
                o[mtQ][dt] = __builtin_amdgcn_mfma_f32_16x16x32_bf16(av[dt][0], bp[mtQ][0], o[mtQ][dt], 0, 0, 0);
                o[mtQ][dt] = __builtin_amdgcn_mfma_f32_16x16x32_bf16(av[dt][1], bp[mtQ][1], o[mtQ][dt], 0, 0, 0);
            }
        }
        __builtin_amdgcn_s_setprio(0);

        if (t < 62) { VM2; } else if (t == 62) { VM0; }
        __builtin_amdgcn_s_barrier();
        __builtin_amdgcn_sched_barrier(0);
        cur += 8192; if (cur >= 24576) cur -= 24576;
    }

    // epilogue: transpose O^T -> O via per-wave LDS scratch, then coalesced write
    __syncthreads();
    u16* scratch = lds_all + wid * 2048;     // [q 32][d 64] per wave (4 KB)
#pragma unroll
    for (int mtQ = 0; mtQ < 2; ++mtQ) {
        float rl = 1.f / lacc[mtQ][0];
#pragma unroll
        for (int dt = 0; dt < 4; ++dt) {
            uint2 ov;
            ov.x = pk2bf(o[mtQ][dt][0] * rl, o[mtQ][dt][1] * rl);
            ov.y = pk2bf(o[mtQ][dt][2] * rl, o[mtQ][dt][3] * rl);
            *(uint2*)&scratch[(mtQ * 16 + l15) * 64 + dt * 16 + quad * 4] = ov;
        }
    }
    __syncthreads();
#pragma unroll
    for (int p = 0; p < 4; ++p) {
        int q_local = p * 8 + (lane >> 3);
        int dcol = (lane & 7) * 8;
        bf16x8 v = *(const bf16x8*)&scratch[q_local * 64 + dcol];
        *(bf16x8*)&O[(size_t)(q0 + q_local) * INNER + h * 64 + dcol] = v;
    }
}

extern "C" void kernel_launch(void* const* d_in, const int* in_sizes, int n_in,
                              void* d_out, int out_size, void* d_ws, size_t ws_size,
                              hipStream_t stream) {
    const float* x     = (const float*)d_in[0];
    const float* pe    = (const float*)d_in[1];
    const float* w_qkv = (const float*)d_in[2];
    const float* w_out = (const float*)d_in[3];
    const float* ln_g  = (const float*)d_in[4];
    const float* ln_b  = (const float*)d_in[5];
    float* out = (float*)d_out;

    char* ws = (char*)d_ws;
    u16* xn  = (u16*)ws;  ws += (size_t)N_TOK * DMODEL * 2;
    u16* wq  = (u16*)ws;  ws += (size_t)3 * INNER * DMODEL * 2;
    u16* wo  = (u16*)ws;  ws += (size_t)DMODEL * INNER * 2;
    u16* qkv = (u16*)ws;  ws += (size_t)N_TOK * DMODEL * 2;
    u16* Qr  = (u16*)ws;  ws += (size_t)NH * N_TOK * DHEAD * 2;
    u16* Kr  = (u16*)ws;  ws += (size_t)NH * N_TOK * DHEAD * 2;
    u16* Vt  = (u16*)ws;  ws += (size_t)NH * DHEAD * N_TOK * 2;
    u16* Ob  = (u16*)ws;  ws += (size_t)N_TOK * INNER * 2;

    prep<<<4096 + 2048 + 512, 256, 0, stream>>>(x, ln_g, ln_b, xn, w_qkv, wq, w_out, wo);
    gemm256<1><<<dim3((N_TOK / 256) * (DMODEL / 256)), 512, 0, stream>>>(xn, wq, qkv, N_TOK, DMODEL, DMODEL);
    rope_vt<<<4096 + 1024, 256, 0, stream>>>(qkv, pe, Qr, Kr, Vt);
    flash_attn<<<dim3(N_TOK / 256, NH), 512, 0, stream>>>(Qr, Kr, Vt, Ob);
    gemm256<0><<<dim3((N_TOK / 256) * (DMODEL / 256)), 512, 0, stream>>>(Ob, wo, out, N_TOK, DMODEL, INNER);
}

// Round 9
// 351.091 us; speedup vs baseline: 1.7670x; 1.0013x over previous
//
#include <hip/hip_runtime.h>
#include <hip/hip_bf16.h>

typedef unsigned short u16;
typedef __attribute__((ext_vector_type(8))) short bf16x8;
typedef __attribute__((ext_vector_type(4))) float f32x4;

#define N_TOK 4096
#define DMODEL 3072
#define NH 16
#define DHEAD 64
#define INNER 1024
#define SCALE_LOG2E 0.18033688011112042f  /* (1/8) * log2(e) */

__device__ __forceinline__ u16 f2bf(float f) {
    union { float f; unsigned u; } un; un.f = f;
    unsigned r = un.u + 0x7fffu + ((un.u >> 16) & 1u);
    return (u16)(r >> 16);
}
__device__ __forceinline__ float bf2f(u16 u) {
    union { unsigned u; float f; } x; x.u = ((unsigned)u) << 16; return x.f;
}
// pack two f32 -> two bf16 (round-half-up) in 3 VALU ops; a -> low 16
__device__ __forceinline__ unsigned pk2bf(float a, float b) {
    union { float f; unsigned u; } ua, ub; ua.f = a; ub.f = b;
    return __builtin_amdgcn_perm(ub.u + 0x8000u, ua.u + 0x8000u, 0x07060302u);
}
__device__ __forceinline__ void load_lds16(const u16* g, u16* l) {
    __builtin_amdgcn_global_load_lds(
        (const __attribute__((address_space(1))) unsigned int*)g,
        (__attribute__((address_space(3))) unsigned int*)l, 16, 0, 0);
}

// Build PV B-operand in-register from packed exp2(S^T) words.
// Output: lane (l15,quad) holds keys [8*quad, 8*quad+8) for col q=l15.
__device__ __forceinline__ bf16x8 build_bp(unsigned u0, unsigned u1,
                                           unsigned w0, unsigned w1) {
    auto a = __builtin_amdgcn_permlane32_swap(u0, w0, false, false);
    auto b = __builtin_amdgcn_permlane16_swap(a[0], a[1], false, false);
    auto c = __builtin_amdgcn_permlane32_swap(u1, w1, false, false);
    auto d = __builtin_amdgcn_permlane16_swap(c[0], c[1], false, false);
    union { unsigned w[4]; bf16x8 v; } r;
    r.w[0] = b[0]; r.w[1] = d[0]; r.w[2] = b[1]; r.w[3] = d[1];
    return r.v;
}

// ------- Fused prep: LN rows (blocks 0..4095), wq cvt (4096..6143), --------
// ------- wo cvt (6144..6655). --------
__global__ __launch_bounds__(256) void prep(const float* __restrict__ x,
                                            const float* __restrict__ g,
                                            const float* __restrict__ b,
                                            u16* __restrict__ xn,
                                            const float* __restrict__ w_qkv,
                                            u16* __restrict__ wq,
                                            const float* __restrict__ w_out,
                                            u16* __restrict__ wo) {
    int bid = blockIdx.x;
    int tid = threadIdx.x;
    if (bid < 4096) {
        int row = bid;
        const float4* xr = (const float4*)(x + (size_t)row * DMODEL);
        float4 v[3];
        float s = 0.f, ss = 0.f;
#pragma unroll
        for (int i = 0; i < 3; ++i) {
            v[i] = xr[i * 256 + tid];
            s  += v[i].x + v[i].y + v[i].z + v[i].w;
            ss += v[i].x * v[i].x + v[i].y * v[i].y + v[i].z * v[i].z + v[i].w * v[i].w;
        }
#pragma unroll
        for (int off = 32; off; off >>= 1) {
            s  += __shfl_xor(s, off);
            ss += __shfl_xor(ss, off);
        }
        __shared__ float red[8];
        int wid = tid >> 6, lane = tid & 63;
        if (lane == 0) { red[wid] = s; red[wid + 4] = ss; }
        __syncthreads();
        s  = red[0] + red[1] + red[2] + red[3];
        ss = red[4] + red[5] + red[6] + red[7];
        float mean = s * (1.f / DMODEL);
        float var  = ss * (1.f / DMODEL) - mean * mean;
        float rstd = rsqrtf(var + 1e-5f);
        ushort4* orow = (ushort4*)(xn + (size_t)row * DMODEL);
#pragma unroll
        for (int i = 0; i < 3; ++i) {
            float4 gg = ((const float4*)g)[i * 256 + tid];
            float4 bb = ((const float4*)b)[i * 256 + tid];
            ushort4 o;
            o.x = f2bf((v[i].x - mean) * rstd * gg.x + bb.x);
            o.y = f2bf((v[i].y - mean) * rstd * gg.y + bb.y);
            o.z = f2bf((v[i].z - mean) * rstd * gg.z + bb.z);
            o.w = f2bf((v[i].w - mean) * rstd * gg.w + bb.w);
            orow[i * 256 + tid] = o;
        }
    } else if (bid < 4096 + 2048) {
        const int n4 = 3 * INNER * DMODEL / 4;
        for (int i = (bid - 4096) * 256 + tid; i < n4; i += 2048 * 256) {
            float4 v = ((const float4*)w_qkv)[i];
            ushort4 o;
            o.x = f2bf(v.x); o.y = f2bf(v.y); o.z = f2bf(v.z); o.w = f2bf(v.w);
            ((ushort4*)wq)[i] = o;
        }
    } else {
        const int n4 = DMODEL * INNER / 4;
        for (int i = (bid - 6144) * 256 + tid; i < n4; i += 512 * 256) {
            float4 v = ((const float4*)w_out)[i];
            ushort4 o;
            o.x = f2bf(v.x); o.y = f2bf(v.y); o.z = f2bf(v.z); o.w = f2bf(v.w);
            ((ushort4*)wo)[i] = o;
        }
    }
}

// ============ GEMM 256x256 8-phase (T2+T3+T4+T5), C = A * B^T ============
// (unchanged — verified R2-R8; control)

#define VM6 asm volatile("s_waitcnt vmcnt(6)" ::: "memory")
#define VM4 asm volatile("s_waitcnt vmcnt(4)" ::: "memory")
#define VM0 asm volatile("s_waitcnt vmcnt(0)" ::: "memory")
#define LGK8 asm volatile("s_waitcnt lgkmcnt(8)" ::: "memory")
#define NOPS ((void)0)

#define ST_A(d, h, t) do { \
    load_lds16(pA##h##0 + (size_t)(t) * 64, &lds[(d) * 16384 + (h) * 8192 + dq]); \
    load_lds16(pA##h##1 + (size_t)(t) * 64, &lds[(d) * 16384 + (h) * 8192 + dq + 512]); \
  } while (0)
#define ST_B(d, h, t) do { \
    load_lds16(pB##h##0 + (size_t)(t) * 64, &lds[32768 + (d) * 16384 + (h) * 8192 + dq]); \
    load_lds16(pB##h##1 + (size_t)(t) * 64, &lds[32768 + (d) * 16384 + (h) * 8192 + dq + 512]); \
  } while (0)

#define PHASE(d, p, STAGE, PRE, POST) do { \
    bf16x8 afr[2][2]; \
    if ((p) == 0) { \
      _Pragma("unroll") for (int nf = 0; nf < 4; ++nf) { \
        bfr[nf][0] = *(const bf16x8*)&lds[(d) * 16384 + baseB + nf * 1024 + c0]; \
        bfr[nf][1] = *(const bf16x8*)&lds[(d) * 16384 + baseB + nf * 1024 + c1]; \
      } \
    } \
    _Pragma("unroll") for (int mfl = 0; mfl < 2; ++mfl) { \
      afr[mfl][0] = *(const bf16x8*)&lds[(d) * 16384 + (p) * 4096 + mfl * 1024 + baseA + c0]; \
      afr[mfl][1] = *(const bf16x8*)&lds[(d) * 16384 + (p) * 4096 + mfl * 1024 + baseA + c1]; \
    } \
    STAGE; \
    PRE; \
    __builtin_amdgcn_s_barrier(); \
    asm volatile("s_waitcnt lgkmcnt(0)" ::: "memory"); \
    __builtin_amdgcn_sched_barrier(0); \
    __builtin_amdgcn_s_setprio(1); \
    _Pragma("unroll") for (int mfl = 0; mfl < 2; ++mfl) \
      _Pragma("unroll") for (int nf = 0; nf < 4; ++nf) { \
        acc[(p) * 2 + mfl][nf] = __builtin_amdgcn_mfma_f32_16x16x32_bf16(afr[mfl][0], bfr[nf][0], acc[(p) * 2 + mfl][nf], 0, 0, 0); \
        acc[(p) * 2 + mfl][nf] = __builtin_amdgcn_mfma_f32_16x16x32_bf16(afr[mfl][1], bfr[nf][1], acc[(p) * 2 + mfl][nf], 0, 0, 0); \
      } \
    __builtin_amdgcn_s_setprio(0); \
    POST; \
    __builtin_amdgcn_s_barrier(); \
  } while (0)

template <int CBF16>
__global__ __launch_bounds__(512, 2) void gemm256(const u16* __restrict__ A,
                                                  const u16* __restrict__ B,
                                                  void* __restrict__ C,
                                                  int M, int Nn, int K) {
    __shared__ u16 lds[65536];   // A: [2][256][64] @0 ; B: same @32768 (128 KiB)
    const int tid = threadIdx.x;
    const int lane = tid & 63, wid = tid >> 6;
    const int wm = wid >> 2, wn = wid & 3;
    const int l15 = lane & 15, quad = lane >> 4;
    const int sw = l15 & 7;

    // XCD-aware bijective swizzle (gridDim.x % 8 == 0)
    int nbx = Nn >> 8;
    int cpx = gridDim.x >> 3;
    int wg = (blockIdx.x & 7) * cpx + (blockIdx.x >> 3);
    int m0 = (wg / nbx) << 8, n0 = (wg % nbx) << 8;

    // per-thread ds_read bases (u16 units) and swizzled chunk offsets
    const int baseA = wm * 2048 + l15 * 64;
    const int baseB = 32768 + wn * 4096 + l15 * 64;
    const int c0 = (quad ^ sw) * 8;
    const int c1 = ((4 + quad) ^ sw) * 8;
    const int dq = wid * 1024;                 // stage LDS base (j adds 512)

    // stage source pointers: LDS row ell -> global row, pre-swizzled col
    const u16 *pA00, *pA01, *pA10, *pA11, *pB00, *pB01, *pB10, *pB11;
    {
        int scol = ((lane & 7) ^ (lane >> 3)) * 8;
#define MKSRC(h, j, PA, PB) { \
        int ell = (h) * 128 + (wid * 2 + (j)) * 8 + (lane >> 3); \
        int g = ell >> 6, wmh = (ell >> 5) & 1, r = ell & 31; \
        PA = A + (size_t)(m0 + wmh * 128 + g * 32 + r) * K + scol; \
        PB = B + (size_t)(n0 + ell) * K + scol; }
        MKSRC(0, 0, pA00, pB00) MKSRC(0, 1, pA01, pB01)
        MKSRC(1, 0, pA10, pB10) MKSRC(1, 1, pA11, pB11)
#undef MKSRC
    }

    f32x4 acc[8][4];
    f32x4 zero4 = {0.f, 0.f, 0.f, 0.f};
#pragma unroll
    for (int i = 0; i < 8; ++i)
#pragma unroll
        for (int j = 0; j < 4; ++j) acc[i][j] = zero4;
    bf16x8 bfr[4][2];

    // prologue: tile0 (4 halves) -> buf0, tile1 (B0,B1,A0) -> buf1
    ST_B(0, 0, 0); ST_B(0, 1, 0); ST_A(0, 0, 0); ST_A(0, 1, 0);
    ST_B(1, 0, 1); ST_B(1, 1, 1); ST_A(1, 0, 1);
    VM6;                                   // tile0 landed; 3 halves in flight
    __builtin_amdgcn_s_barrier();

    const int NIT = (K >> 7) - 1;          // T/2 - 1 iterations
    for (int i = 0; i < NIT; ++i) {
        int t = 2 * i;
        PHASE(0, 0, ST_A(1, 1, t + 1), LGK8, NOPS);
        PHASE(0, 1, ST_B(0, 0, t + 2), NOPS, NOPS);
        PHASE(0, 2, ST_B(0, 1, t + 2), NOPS, NOPS);
        PHASE(0, 3, ST_A(0, 0, t + 2), NOPS, VM6);
        PHASE(1, 0, ST_A(0, 1, t + 2), LGK8, NOPS);
        PHASE(1, 1, ST_B(1, 0, t + 3), NOPS, NOPS);
        PHASE(1, 2, ST_B(1, 1, t + 3), NOPS, NOPS);
        PHASE(1, 3, ST_A(1, 0, t + 3), NOPS, VM6);
    }
    {   // epilogue: tiles T-2 (buf0), T-1 (buf1); only (T-1).A1 left to stage
        int T = K >> 6;
        PHASE(0, 0, ST_A(1, 1, T - 1), LGK8, NOPS);
        PHASE(0, 1, NOPS, NOPS, NOPS);
        PHASE(0, 2, NOPS, NOPS, NOPS);
        PHASE(0, 3, NOPS, NOPS, VM0);
        PHASE(1, 0, NOPS, LGK8, NOPS);
        PHASE(1, 1, NOPS, NOPS, NOPS);
        PHASE(1, 2, NOPS, NOPS, NOPS);
        PHASE(1, 3, NOPS, NOPS, NOPS);
    }

    // C write: rr = m0 + wm*128 + mf*16 + quad*4 + r ; cc = n0 + wn*64 + nf*16 + l15
#pragma unroll
    for (int mf = 0; mf < 8; ++mf)
#pragma unroll
        for (int nf = 0; nf < 4; ++nf)
#pragma unroll
            for (int r = 0; r < 4; ++r) {
                int rr = m0 + wm * 128 + mf * 16 + quad * 4 + r;
                int cc = n0 + wn * 64 + nf * 16 + l15;
                if (CBF16)
                    ((u16*)C)[(size_t)rr * Nn + cc] = f2bf(acc[mf][nf][r]);
                else
                    ((float*)C)[(size_t)rr * Nn + cc] = acc[mf][nf][r];
            }
}

// ------- Fused RoPE (blocks 0..4095) + V transpose (4096..5119) -----------
__global__ __launch_bounds__(256) void rope_vt(const u16* __restrict__ qkv,
                                               const float* __restrict__ pe,
                                               u16* __restrict__ Qr,
                                               u16* __restrict__ Kr,
                                               u16* __restrict__ Vt) {
    int bid = blockIdx.x;
    int tid = threadIdx.x;
    if (bid < 4096) {
        int n = bid;
        const u16* qrow = qkv + (size_t)n * DMODEL;
        const float4* pen = (const float4*)(pe + (size_t)n * 128);
#pragma unroll
        for (int it = 0; it < 2; ++it) {
            int p = it * 256 + tid;      // pair index 0..511
            int h = p >> 5, i = p & 31;
            float4 w = pen[i];
            size_t obase = ((size_t)h * N_TOK + n) * DHEAD + 2 * i;
            unsigned qq = *(const unsigned*)&qrow[h * 64 + 2 * i];
            float q0 = bf2f((u16)qq), q1 = bf2f((u16)(qq >> 16));
            *(unsigned*)&Qr[obase] = pk2bf((w.x * q0 + w.y * q1) * SCALE_LOG2E,
                                           (w.z * q0 + w.w * q1) * SCALE_LOG2E);
            unsigned kk = *(const unsigned*)&qrow[INNER + h * 64 + 2 * i];
            float k0 = bf2f((u16)kk), k1 = bf2f((u16)(kk >> 16));
            *(unsigned*)&Kr[obase] = pk2bf(w.x * k0 + w.y * k1, w.z * k0 + w.w * k1);
        }
    } else {
        __shared__ u16 t[64][65];
        int tb = bid - 4096;
        int n0 = (tb & 63) * 64;
        int h = tb >> 6;
#pragma unroll
        for (int it = 0; it < 4; ++it) {
            int nr = it * 16 + (tid >> 4);
            int dc = (tid & 15) * 4;
            ushort4 v = *(const ushort4*)&qkv[(size_t)(n0 + nr) * DMODEL + 2 * INNER + h * 64 + dc];
            t[dc + 0][nr] = v.x; t[dc + 1][nr] = v.y; t[dc + 2][nr] = v.z; t[dc + 3][nr] = v.w;
        }
        __syncthreads();
#pragma unroll
        for (int it = 0; it < 4; ++it) {
            int dr = it * 16 + (tid >> 4);
            int nc = (tid & 15) * 4;
            ushort4 v;
            v.x = t[dr][nc]; v.y = t[dr][nc + 1]; v.z = t[dr][nc + 2]; v.w = t[dr][nc + 3];
            *(ushort4*)&Vt[((size_t)h * 64 + dr) * N_TOK + n0 + nc] = v;
        }
    }
}

// ---------------- Flash attention: R8 pipeline @ 2 blocks/CU --------------
// R9: geometry-only change vs R8. Counters showed VALU(45%)+LDS(~43%)+
// MFMA(33%) summing to ~100% — zero pipe overlap at 1 block/CU (2 waves/
// SIMD, barrier idles whole CU). Now 4 waves/block, QBLK=128, grid (32,16)
// = 512 blocks = 2 blocks/CU = 4 waves/SIMD from independent blocks —
// barriers decouple, pipes can overlap. Pipeline byte-identical to R8:
// 3x16KB rotation, split lgkm(8)/lgkm(0) waits, counted vmcnt (VM4 now:
// 4 loads/stage), one barrier/tile, in-register P exchange.

#define FA_STAGE3(dst, kt) do { \
    load_lds16(&Kh[(size_t)((kt) + krow) * DHEAD + csw], &lds_all[(dst) + kbase]); \
    load_lds16(&Kh[(size_t)((kt) + krow + 8) * DHEAD + csw], &lds_all[(dst) + kbase + 512]); \
    load_lds16(&Vh[(size_t)krow * N_TOK + (kt) + csw], &lds_all[(dst) + 4096 + kbase]); \
    load_lds16(&Vh[(size_t)(krow + 8) * N_TOK + (kt) + csw], &lds_all[(dst) + 4096 + kbase + 512]); \
  } while (0)

__global__ __launch_bounds__(256, 2) void flash_attn(const u16* __restrict__ Q,
                                                     const u16* __restrict__ K,
                                                     const u16* __restrict__ Vt,
                                                     u16* __restrict__ O) {
    __shared__ u16 lds_all[24576];           // 48 KB: 3 x 16KB K/V rotation
    int tid = threadIdx.x, lane = tid & 63, wid = tid >> 6;
    int l15 = lane & 15, quad = lane >> 4;
    int sw = l15 & 7;
    int h = blockIdx.y;
    int q0 = blockIdx.x * 128 + wid * 32;
    const u16* Qh = Q + (size_t)h * N_TOK * DHEAD;
    const u16* Kh = K + (size_t)h * N_TOK * DHEAD;
    const u16* Vh = Vt + (size_t)h * DHEAD * N_TOK;

    f32x4 zero4 = {0.f, 0.f, 0.f, 0.f};
    bf16x8 ones;
#pragma unroll
    for (int i = 0; i < 8; ++i) ones[i] = (short)0x3F80;  // bf16 1.0

    // Q fragments (B operand): B[n=q=l15][k=dhead]
    bf16x8 aq[2][2];
#pragma unroll
    for (int mtQ = 0; mtQ < 2; ++mtQ)
#pragma unroll
        for (int kc = 0; kc < 2; ++kc)
            aq[mtQ][kc] = *(const bf16x8*)&Qh[(size_t)(q0 + mtQ * 16 + l15) * DHEAD + kc * 32 + quad * 8];

    f32x4 o[2][4], lacc[2];
#pragma unroll
    for (int mtQ = 0; mtQ < 2; ++mtQ) {
#pragma unroll
        for (int dt = 0; dt < 4; ++dt) o[mtQ][dt] = zero4;
        lacc[mtQ] = zero4;
    }

    // staging: wave stages K rows [wid*16, wid*16+16) and V rows same range
    int rowoff = lane >> 3;                      // 0..7
    int krow = wid * 16 + rowoff;                // 0..63 (with +8 variant)
    int kbase = wid * 1024;                      // u16: wid*16 rows * 64
    int csw = ((lane & 7) ^ rowoff) * 8;         // swizzled source column (u16)

    // prologue: tiles 0,1 -> bufs 0,1; wait tile0 (tile1's 4 loads in flight)
    FA_STAGE3(0, 0);
    FA_STAGE3(8192, 64);
    VM4;
    __builtin_amdgcn_s_barrier();
    __builtin_amdgcn_sched_barrier(0);

    int cur = 0;
    for (int t = 0; t < 64; ++t) {
        int stg = cur + 16384; if (stg >= 24576) stg -= 24576;  // (t+2)%3
        bf16x8 bk[4][2], av[4][2];
#pragma unroll
        for (int tt = 0; tt < 4; ++tt)
#pragma unroll
            for (int kc = 0; kc < 2; ++kc)
                bk[tt][kc] = *(const bf16x8*)&lds_all[cur + (tt * 16 + l15) * 64 + (((kc * 4 + quad) ^ sw) * 8)];
        __builtin_amdgcn_sched_barrier(0);
#pragma unroll
        for (int tt = 0; tt < 4; ++tt)
#pragma unroll
            for (int kc = 0; kc < 2; ++kc)
                av[tt][kc] = *(const bf16x8*)&lds_all[cur + 4096 + (tt * 16 + l15) * 64 + (((kc * 4 + quad) ^ sw) * 8)];
        __builtin_amdgcn_sched_barrier(0);
        if (t < 62) FA_STAGE3(stg, (t + 2) * 64);
        asm volatile("s_waitcnt lgkmcnt(8)" ::: "memory");   // bk ready; av in flight
        __builtin_amdgcn_sched_barrier(0);

        bf16x8 bp[2][2];
#pragma unroll
        for (int mtQ = 0; mtQ < 2; ++mtQ) {
            f32x4 s[4];
            __builtin_amdgcn_s_setprio(1);
#pragma unroll
            for (int ntK = 0; ntK < 4; ++ntK) {
                f32x4 t0 = __builtin_amdgcn_mfma_f32_16x16x32_bf16(bk[ntK][0], aq[mtQ][0], zero4, 0, 0, 0);
                s[ntK] = __builtin_amdgcn_mfma_f32_16x16x32_bf16(bk[ntK][1], aq[mtQ][1], t0, 0, 0, 0);
            }
            __builtin_amdgcn_s_setprio(0);
            unsigned pw[4][2];
#pragma unroll
            for (int ntK = 0; ntK < 4; ++ntK) {
                pw[ntK][0] = pk2bf(__builtin_amdgcn_exp2f(s[ntK][0]), __builtin_amdgcn_exp2f(s[ntK][1]));
                pw[ntK][1] = pk2bf(__builtin_amdgcn_exp2f(s[ntK][2]), __builtin_amdgcn_exp2f(s[ntK][3]));
            }
            bp[mtQ][0] = build_bp(pw[0][0], pw[0][1], pw[1][0], pw[1][1]);
            bp[mtQ][1] = build_bp(pw[2][0], pw[2][1], pw[3][0], pw[3][1]);
        }

        asm volatile("s_waitcnt lgkmcnt(0)" ::: "memory");   // av ready
        __builtin_amdgcn_sched_barrier(0);
        __builtin_amdgcn_s_setprio(1);
#pragma unroll
        for (int mtQ = 0; mtQ < 2; ++mtQ) {
            lacc[mtQ] = __builtin_amdgcn_mfma_f32_16x16x32_bf16(ones, bp[mtQ][0], lacc[mtQ], 0, 0, 0);
            lacc[mtQ] = __builtin_amdgcn_mfma_f32_16x16x32_bf16(ones, bp[mtQ][1], lacc[mtQ], 0, 0, 0);
#pragma unroll
            for (int dt = 0; dt < 4; ++dt) {
                o[mtQ][dt] = __builtin_amdgcn_mfma_f32_16x16x32_bf16(av[dt][0], bp[mtQ][0], o[mtQ][dt], 0, 0, 0);
                o[mtQ][dt] = __builtin_amdgcn_mfma_f32_16x16x32_bf16(av[dt][1], bp[mtQ][1], o[mtQ][dt], 0, 0, 0);
            }
        }
        __builtin_amdgcn_s_setprio(0);

        if (t < 62) { VM4; } else if (t == 62) { VM0; }
        __builtin_amdgcn_s_barrier();
        __builtin_amdgcn_sched_barrier(0);
        cur += 8192; if (cur >= 24576) cur -= 24576;
    }

    // epilogue: transpose O^T -> O via per-wave LDS scratch, then coalesced write
    __syncthreads();
    u16* scratch = lds_all + wid * 2048;     // [q 32][d 64] per wave (4 KB)
#pragma unroll
    for (int mtQ = 0; mtQ < 2; ++mtQ) {
        float rl = 1.f / lacc[mtQ][0];
#pragma unroll
        for (int dt = 0; dt < 4; ++dt) {
            uint2 ov;
            ov.x = pk2bf(o[mtQ][dt][0] * rl, o[mtQ][dt][1] * rl);
            ov.y = pk2bf(o[mtQ][dt][2] * rl, o[mtQ][dt][3] * rl);
            *(uint2*)&scratch[(mtQ * 16 + l15) * 64 + dt * 16 + quad * 4] = ov;
        }
    }
    __syncthreads();
#pragma unroll
    for (int p = 0; p < 4; ++p) {
        int q_local = p * 8 + (lane >> 3);
        int dcol = (lane & 7) * 8;
        bf16x8 v = *(const bf16x8*)&scratch[q_local * 64 + dcol];
        *(bf16x8*)&O[(size_t)(q0 + q_local) * INNER + h * 64 + dcol] = v;
    }
}

extern "C" void kernel_launch(void* const* d_in, const int* in_sizes, int n_in,
                              void* d_out, int out_size, void* d_ws, size_t ws_size,
                              hipStream_t stream) {
    const float* x     = (const float*)d_in[0];
    const float* pe    = (const float*)d_in[1];
    const float* w_qkv = (const float*)d_in[2];
    const float* w_out = (const float*)d_in[3];
    const float* ln_g  = (const float*)d_in[4];
    const float* ln_b  = (const float*)d_in[5];
    float* out = (float*)d_out;

    char* ws = (char*)d_ws;
    u16* xn  = (u16*)ws;  ws += (size_t)N_TOK * DMODEL * 2;
    u16* wq  = (u16*)ws;  ws += (size_t)3 * INNER * DMODEL * 2;
    u16* wo  = (u16*)ws;  ws += (size_t)DMODEL * INNER * 2;
    u16* qkv = (u16*)ws;  ws += (size_t)N_TOK * DMODEL * 2;
    u16* Qr  = (u16*)ws;  ws += (size_t)NH * N_TOK * DHEAD * 2;
    u16* Kr  = (u16*)ws;  ws += (size_t)NH * N_TOK * DHEAD * 2;
    u16* Vt  = (u16*)ws;  ws += (size_t)NH * DHEAD * N_TOK * 2;
    u16* Ob  = (u16*)ws;  ws += (size_t)N_TOK * INNER * 2;

    prep<<<4096 + 2048 + 512, 256, 0, stream>>>(x, ln_g, ln_b, xn, w_qkv, wq, w_out, wo);
    gemm256<1><<<dim3((N_TOK / 256) * (DMODEL / 256)), 512, 0, stream>>>(xn, wq, qkv, N_TOK, DMODEL, DMODEL);
    rope_vt<<<4096 + 1024, 256, 0, stream>>>(qkv, pe, Qr, Kr, Vt);
    flash_attn<<<dim3(N_TOK / 128, NH), 256, 0, stream>>>(Qr, Kr, Vt, Ob);
    gemm256<0><<<dim3((N_TOK / 256) * (DMODEL / 256)), 512, 0, stream>>>(Ob, wo, out, N_TOK, DMODEL, INNER);
}